// Round 6
// baseline (896.509 us; speedup 1.0000x reference)
//
#include <hip/hip_runtime.h>
#include <hip/hip_bf16.h>
#include <cstdint>

typedef short  bf16x8 __attribute__((ext_vector_type(8)));
typedef float  f32x4  __attribute__((ext_vector_type(4)));
typedef unsigned short u16x8 __attribute__((ext_vector_type(8)));

#define GLDS(gp, lp) __builtin_amdgcn_global_load_lds( \
    (const __attribute__((address_space(1))) void*)(gp), \
    (__attribute__((address_space(3))) void*)(lp), 16, 0, 0)

static constexpr int   MROWS = 16384;   // B*N = 16*1024
static constexpr int   N3    = 3072;    // 3*C
static constexpr int   NT    = 48;      // K-tiles of 64 (logical K = 3072)
static constexpr float SCALE = 0.125f;  // 8/64

__device__ __forceinline__ unsigned short f2bf(float f) {
  union { float f; unsigned u; } c; c.f = f;
  return (unsigned short)((c.u + 0x7fffu + ((c.u >> 16) & 1u)) >> 16);
}
__device__ __forceinline__ float bf2f(unsigned short h) {
  union { unsigned u; float f; } c; c.u = ((unsigned)h) << 16;
  return c.f;
}
// swap the two 5-bit (h,w) fields within each batch's 1024 rows (involution)
__device__ __forceinline__ int permrow(int m) {
  return (m & ~1023) | ((m & 31) << 5) | ((m >> 5) & 31);
}

// ---- split fp32 activations: row layout [hi(1024) | lo(1024)] bf16 ----
__global__ __launch_bounds__(256) void split_x(const float* __restrict__ src,
                                               unsigned short* __restrict__ dst) {
  int idx = blockIdx.x * 256 + threadIdx.x;
  int m = idx >> 7, k8 = (idx & 127) << 3;
  const float* s = src + (size_t)m * 1024 + k8;
  float4 v0 = *(const float4*)s;
  float4 v1 = *(const float4*)(s + 4);
  float vals[8] = {v0.x, v0.y, v0.z, v0.w, v1.x, v1.y, v1.z, v1.w};
  u16x8 hi, lo;
#pragma unroll
  for (int i = 0; i < 8; ++i) {
    unsigned short h = f2bf(vals[i]);
    hi[i] = h;
    lo[i] = f2bf(vals[i] - bf2f(h));
  }
  unsigned short* d = dst + (size_t)m * 2048 + k8;
  *(u16x8*)(d)        = hi;
  *(u16x8*)(d + 1024) = lo;
}

// ---- split fp32 weights into tripled [hi | lo | hi] bf16 ----
__global__ __launch_bounds__(256) void split_w(const float* __restrict__ src,
                                               unsigned short* __restrict__ dst) {
  int idx = blockIdx.x * 256 + threadIdx.x;
  int n = idx >> 7, k8 = (idx & 127) << 3;
  const float* s = src + (size_t)n * 1024 + k8;
  float4 v0 = *(const float4*)s;
  float4 v1 = *(const float4*)(s + 4);
  float vals[8] = {v0.x, v0.y, v0.z, v0.w, v1.x, v1.y, v1.z, v1.w};
  u16x8 hi, lo;
#pragma unroll
  for (int i = 0; i < 8; ++i) {
    unsigned short h = f2bf(vals[i]);
    hi[i] = h;
    lo[i] = f2bf(vals[i] - bf2f(h));
  }
  unsigned short* d = dst + (size_t)n * N3 + k8;
  *(u16x8*)(d)        = hi;
  *(u16x8*)(d + 1024) = lo;
  *(u16x8*)(d + 2048) = hi;
}

// ================= 256x256 8-wave GEMM, 4-phase/K-tile counted-vmcnt ======
// C[m][n] = sum over logical K=3072: seg0 Ahi*Bhi, seg1 Ahi*Blo, seg2 Alo*Bhi
// A row layout [hi|lo] stride 2048 (rewind at K-tile 16); B tripled stride 3072.
// LDS: 2 bufs x (A 32KB + B 32KB), st_16x32 XOR swizzle via pre-swizzled source.
// Phases balanced 8/4 reads: ph{1,3} read a[0..3]+b[0..3], ph{2,4} read a[4..7].
// Grid: per-XCD chunks, n-fast inside chunk -> the 12 blocks sharing an A
// m-panel run concurrently on ONE XCD (A HBM-fetched once; B cycles from LLC).
__global__ __launch_bounds__(512, 2) void gemm256(const unsigned short* __restrict__ A,
                                                  const unsigned short* __restrict__ Bm,
                                                  unsigned short* __restrict__ Cq) {
  __shared__ unsigned char smem[131072];
  const int tid = threadIdx.x;
  const int w = tid >> 6, l = tid & 63;
  const int wr = w >> 2, wc = w & 3;          // 2 x 4 wave grid

  // XCD-chunked, n-fast within chunk (768 = 8 XCDs x 8 m-panels x 12 n-panels)
  const int bid = blockIdx.x;
  const int xcd = bid & 7, ic = bid >> 3;
  const int m0 = (xcd * 8 + ic / 12) << 8;
  const int n0 = (ic % 12) << 8;

  // staging: wave w owns rows w*32..w*32+31 of each 16KB unit; pre-swizzled k src
  const int ske = ((l & 3) * 8) ^ ((l >= 32) ? 16 : 0);
  const unsigned short* gA0 = A  + (size_t)(m0 + w * 32 + (l >> 2)) * 2048 + ske;
  const unsigned short* gA1 = gA0 + 16 * 2048;
  const unsigned short* gB0 = Bm + (size_t)(n0 + w * 32 + (l >> 2)) * 3072 + ske;
  const unsigned short* gB1 = gB0 + (size_t)16 * 3072;
  int kA = 0, kB = 0;                         // k-elem offset of K-tile being staged

  // swizzled ds_read lane offset (16B frag at row lr, k-group l>>4)
  const int lr = l & 15;
  const int laneoff = ((lr * 64) + ((l >> 4) * 16)) ^ ((lr & 8) << 2);

#define STAGE_A(pb, kk) do { \
    GLDS(gA0 + kA + (kk) * 32, smem + (pb) * 65536 + (4 * w + (kk)) * 1024); \
    GLDS(gA1 + kA + (kk) * 32, smem + (pb) * 65536 + (4 * w + 2 + (kk)) * 1024); } while (0)
#define STAGE_B(pb, kk) do { \
    GLDS(gB0 + kB + (kk) * 32, smem + (pb) * 65536 + 32768 + (4 * w + (kk)) * 1024); \
    GLDS(gB1 + kB + (kk) * 32, smem + (pb) * 65536 + 32768 + (4 * w + 2 + (kk)) * 1024); } while (0)
#define MFMA(af, bf, c) __builtin_amdgcn_mfma_f32_16x16x32_bf16(af, bf, c, 0, 0, 0)

  f32x4 acc[8][4] = {};

  // ---- prologue: stage K-tile 0 (A-kk0, B-kk0 oldest -> vmcnt(4) gates them) --
  STAGE_A(0, 0); STAGE_B(0, 0); STAGE_A(0, 1); STAGE_B(0, 1);
  kA = 64; kB = 64;
  asm volatile("s_waitcnt vmcnt(4)" ::: "memory");
  __builtin_amdgcn_s_barrier();

  for (int t = 0; t < NT; ++t) {
    const int p = t & 1, q = p ^ 1;
    const unsigned char* rb = smem + p * 65536;
    bf16x8 a[4], b[4];

    // ---------- phase 1: kk0, mi 0-3 (reads a0-3 + b0-3); stage A-kk0(t+1) ----
    if (t < NT - 1) STAGE_A(q, 0);
#pragma unroll
    for (int mi = 0; mi < 4; ++mi)
      a[mi] = *(const bf16x8*)(rb + (wr * 8 + mi) * 2048 + laneoff);
#pragma unroll
    for (int ni = 0; ni < 4; ++ni)
      b[ni] = *(const bf16x8*)(rb + 32768 + (wc * 4 + ni) * 2048 + laneoff);
    __builtin_amdgcn_s_barrier();
    asm volatile("s_waitcnt lgkmcnt(0)" ::: "memory");
    __builtin_amdgcn_sched_barrier(0);
    __builtin_amdgcn_s_setprio(1);
#pragma unroll
    for (int mi = 0; mi < 4; ++mi)
#pragma unroll
      for (int ni = 0; ni < 4; ++ni)
        acc[mi][ni] = MFMA(a[mi], b[ni], acc[mi][ni]);
    __builtin_amdgcn_s_setprio(0);
    __builtin_amdgcn_s_barrier();

    // ---------- phase 2: kk0, mi 4-7 (reads a4-7; b held); stage B-kk0(t+1) ---
    if (t < NT - 1) STAGE_B(q, 0);
#pragma unroll
    for (int mi = 0; mi < 4; ++mi)
      a[mi] = *(const bf16x8*)(rb + (wr * 8 + 4 + mi) * 2048 + laneoff);
    __builtin_amdgcn_s_barrier();
    asm volatile("s_waitcnt lgkmcnt(0)" ::: "memory");
    __builtin_amdgcn_sched_barrier(0);
    __builtin_amdgcn_s_setprio(1);
#pragma unroll
    for (int mi = 0; mi < 4; ++mi)
#pragma unroll
      for (int ni = 0; ni < 4; ++ni)
        acc[4 + mi][ni] = MFMA(a[mi], b[ni], acc[4 + mi][ni]);
    __builtin_amdgcn_s_setprio(0);
    // gate: A-kk1(t), B-kk1(t) must have landed (read in ph3/ph4)
    if (t < NT - 1) { asm volatile("s_waitcnt vmcnt(4)" ::: "memory"); }
    else            { asm volatile("s_waitcnt vmcnt(0)" ::: "memory"); }
    __builtin_amdgcn_s_barrier();

    // ---------- phase 3: kk1, mi 0-3 (reads a0-3 + b0-3); stage A-kk1(t+1) ----
    if (t < NT - 1) STAGE_A(q, 1);
#pragma unroll
    for (int mi = 0; mi < 4; ++mi)
      a[mi] = *(const bf16x8*)(rb + (wr * 8 + mi) * 2048 + 1024 + laneoff);
#pragma unroll
    for (int ni = 0; ni < 4; ++ni)
      b[ni] = *(const bf16x8*)(rb + 32768 + (wc * 4 + ni) * 2048 + 1024 + laneoff);
    __builtin_amdgcn_s_barrier();
    asm volatile("s_waitcnt lgkmcnt(0)" ::: "memory");
    __builtin_amdgcn_sched_barrier(0);
    __builtin_amdgcn_s_setprio(1);
#pragma unroll
    for (int mi = 0; mi < 4; ++mi)
#pragma unroll
      for (int ni = 0; ni < 4; ++ni)
        acc[mi][ni] = MFMA(a[mi], b[ni], acc[mi][ni]);
    __builtin_amdgcn_s_setprio(0);
    __builtin_amdgcn_s_barrier();

    // ---------- phase 4: kk1, mi 4-7 (reads a4-7; b held); stage B-kk1(t+1) ---
    if (t < NT - 1) STAGE_B(q, 1);
#pragma unroll
    for (int mi = 0; mi < 4; ++mi)
      a[mi] = *(const bf16x8*)(rb + (wr * 8 + 4 + mi) * 2048 + 1024 + laneoff);
    __builtin_amdgcn_s_barrier();
    asm volatile("s_waitcnt lgkmcnt(0)" ::: "memory");
    __builtin_amdgcn_sched_barrier(0);
    __builtin_amdgcn_s_setprio(1);
#pragma unroll
    for (int mi = 0; mi < 4; ++mi)
#pragma unroll
      for (int ni = 0; ni < 4; ++ni)
        acc[4 + mi][ni] = MFMA(a[mi], b[ni], acc[4 + mi][ni]);
    __builtin_amdgcn_s_setprio(0);
    // gate: A-kk0(t+1), B-kk0(t+1) must have landed (read next tile ph1/ph2)
    if (t < NT - 1) { asm volatile("s_waitcnt vmcnt(4)" ::: "memory"); }
    else            { asm volatile("s_waitcnt vmcnt(0)" ::: "memory"); }
    __builtin_amdgcn_s_barrier();

    kB += 64;
    kA += 64; if (t == 14) kA -= 1024;   // hi-segment rewind: phys(16) = 0
  }

  // ---- epilogue: acc -> bf16 C ----
  const int rq = (l >> 4) * 4;
#pragma unroll
  for (int mi = 0; mi < 8; ++mi)
#pragma unroll
    for (int ni = 0; ni < 4; ++ni) {
      int row = m0 + wr * 128 + mi * 16 + rq;
      int col = n0 + wc * 64 + ni * 16 + lr;
      unsigned short* cp = Cq + (size_t)row * N3 + col;
#pragma unroll
      for (int r = 0; r < 4; ++r)
        cp[(size_t)r * N3] = f2bf(acc[mi][ni][r]);
    }
#undef STAGE_A
#undef STAGE_B
#undef MFMA
}

// ---- per (seq, head): LN(q), LN(k), softmax(q*s @ k^T) @ v; bf16 in ----
// mode 0: write bf16 [hi|lo] rows permrow(m) into a2 (feeds pass-1 GEMM)
// mode 1: write fp32 rows permrow(m) into out (final result)
__global__ __launch_bounds__(256) void attn(const unsigned short* __restrict__ qkv,
                                            const float* __restrict__ gamma,
                                            const float* __restrict__ beta,
                                            float* __restrict__ out,
                                            unsigned short* __restrict__ a2,
                                            int mode) {
  __shared__ float q[32][65], k[32][65], v[32][65];
  __shared__ float pr[32][33];
  __shared__ float mu[64], rs[64], gm[64], bt[64];
  const int tid = threadIdx.x;
  const int s = blockIdx.x >> 4, hd = blockIdx.x & 15;
  const size_t base = (size_t)s * 32 * 3072 + hd * 64;
  if (tid < 64) { gm[tid] = gamma[tid]; bt[tid] = beta[tid]; }
  {
    const int p = tid >> 3, d0 = (tid & 7) * 8;
    size_t r = base + (size_t)p * 3072 + d0;
    u16x8 qa = *(const u16x8*)(qkv + r);
    u16x8 ka = *(const u16x8*)(qkv + r + 1024);
    u16x8 va = *(const u16x8*)(qkv + r + 2048);
#pragma unroll
    for (int j = 0; j < 8; ++j) {
      q[p][d0 + j] = bf2f(qa[j]);
      k[p][d0 + j] = bf2f(ka[j]);
      v[p][d0 + j] = bf2f(va[j]);
    }
  }
  __syncthreads();
  {  // LN stats: 64 rows (q 0-31, k 32-63) x 4 threads each
    const int r = tid >> 2, qt = tid & 3;
    const float* row = (r < 32) ? q[r] : k[r - 32];
    float s1 = 0.f, s2 = 0.f;
#pragma unroll
    for (int d = qt * 16; d < qt * 16 + 16; ++d) { float x = row[d]; s1 += x; s2 += x * x; }
    s1 += __shfl_xor(s1, 1); s2 += __shfl_xor(s2, 1);
    s1 += __shfl_xor(s1, 2); s2 += __shfl_xor(s2, 2);
    if (qt == 0) {
      float m = s1 * 0.015625f;
      mu[r] = m;
      rs[r] = rsqrtf(s2 * 0.015625f - m * m + 1e-5f);
    }
  }
  __syncthreads();
  {
    const int p = tid >> 3, d0 = (tid & 7) * 8;
#pragma unroll
    for (int j = 0; j < 8; ++j) {
      int d = d0 + j;
      q[p][d] = ((q[p][d] - mu[p]) * rs[p] * gm[d] + bt[d]) * SCALE;
      k[p][d] = (k[p][d] - mu[32 + p]) * rs[32 + p] * gm[d] + bt[d];
    }
  }
  __syncthreads();
  {  // logits: 4 per thread
    const int r = tid >> 3, c0 = (tid & 7) * 4;
#pragma unroll
    for (int cc = 0; cc < 4; ++cc) {
      float a = 0.f;
      const float* qr = q[r]; const float* kr = k[c0 + cc];
#pragma unroll
      for (int d = 0; d < 64; ++d) a += qr[d] * kr[d];
      pr[r][c0 + cc] = a;
    }
  }
  __syncthreads();
  {  // softmax: 8 threads per row
    const int r = tid >> 3, c0 = (tid & 7) * 4;
    float e0 = pr[r][c0], e1 = pr[r][c0 + 1], e2 = pr[r][c0 + 2], e3 = pr[r][c0 + 3];
    float mx = fmaxf(fmaxf(e0, e1), fmaxf(e2, e3));
    mx = fmaxf(mx, __shfl_xor(mx, 1));
    mx = fmaxf(mx, __shfl_xor(mx, 2));
    mx = fmaxf(mx, __shfl_xor(mx, 4));
    e0 = __expf(e0 - mx); e1 = __expf(e1 - mx);
    e2 = __expf(e2 - mx); e3 = __expf(e3 - mx);
    float sum = e0 + e1 + e2 + e3;
    sum += __shfl_xor(sum, 1);
    sum += __shfl_xor(sum, 2);
    sum += __shfl_xor(sum, 4);
    float inv = 1.f / sum;
    pr[r][c0] = e0 * inv; pr[r][c0 + 1] = e1 * inv;
    pr[r][c0 + 2] = e2 * inv; pr[r][c0 + 3] = e3 * inv;
  }
  __syncthreads();
  {  // PV + permuted store
    const int p = tid >> 3, d0 = (tid & 7) * 8;
    float o[8] = {};
#pragma unroll
    for (int j = 0; j < 32; ++j) {
      float pj = pr[p][j];
#pragma unroll
      for (int d = 0; d < 8; ++d) o[d] += pj * v[j][d0 + d];
    }
    int pm = permrow(s * 32 + p);
    if (mode == 0) {
      u16x8 hi, lo;
#pragma unroll
      for (int d = 0; d < 8; ++d) {
        unsigned short h = f2bf(o[d]);
        hi[d] = h;
        lo[d] = f2bf(o[d] - bf2f(h));
      }
      unsigned short* dp = a2 + (size_t)pm * 2048 + hd * 64 + d0;
      *(u16x8*)dp          = hi;
      *(u16x8*)(dp + 1024) = lo;
    } else {
      float* op = out + (size_t)pm * 1024 + hd * 64 + d0;
#pragma unroll
      for (int d = 0; d < 8; ++d) op[d] = o[d];
    }
  }
}

extern "C" void kernel_launch(void* const* d_in, const int* in_sizes, int n_in,
                              void* d_out, int out_size, void* d_ws, size_t ws_size,
                              hipStream_t stream) {
  const float* x    = (const float*)d_in[0];
  const float* Wrow = (const float*)d_in[1];
  const float* Wcol = (const float*)d_in[2];
  const float* grow = (const float*)d_in[3];
  const float* brow = (const float*)d_in[4];
  const float* gcol = (const float*)d_in[5];
  const float* bcol = (const float*)d_in[6];
  float* out = (float*)d_out;

  char* ws = (char*)d_ws;
  const size_t szA2 = (size_t)MROWS * 2048 * 2;   // 67108864
  const size_t szB2 = (size_t)N3 * N3 * 2;        // 18874368
  unsigned short* A2   = (unsigned short*)ws;
  unsigned short* B2   = (unsigned short*)(ws + szA2);
  unsigned short* qkvb = (unsigned short*)(ws + szA2 + szB2);  // 16384*3072*2

  // pass 0 (rows)
  split_x<<<8192, 256, 0, stream>>>(x, A2);
  split_w<<<1536, 256, 0, stream>>>(Wrow, B2);
  gemm256<<<768, 512, 0, stream>>>(A2, B2, qkvb);
  attn<<<8192, 256, 0, stream>>>(qkvb, grow, brow, out, A2, 0);  // writes A2 (permuted)
  // pass 1 (cols)
  split_w<<<1536, 256, 0, stream>>>(Wcol, B2);
  gemm256<<<768, 512, 0, stream>>>(A2, B2, qkvb);
  attn<<<8192, 256, 0, stream>>>(qkvb, gcol, bcol, out, A2, 1);  // writes out
}

// Round 7
// 868.390 us; speedup vs baseline: 1.0324x; 1.0324x over previous
//
#include <hip/hip_runtime.h>
#include <hip/hip_bf16.h>
#include <cstdint>

typedef short  bf16x8 __attribute__((ext_vector_type(8)));
typedef float  f32x4  __attribute__((ext_vector_type(4)));
typedef unsigned short u16x8 __attribute__((ext_vector_type(8)));

#define GLDS(gp, lp) __builtin_amdgcn_global_load_lds( \
    (const __attribute__((address_space(1))) void*)(gp), \
    (__attribute__((address_space(3))) void*)(lp), 16, 0, 0)

static constexpr int   MROWS = 16384;   // B*N = 16*1024
static constexpr int   N3    = 3072;    // 3*C
static constexpr int   NT    = 48;      // K-tiles of 64 (logical K = 3072)
static constexpr float SCALE = 0.125f;  // 8/64

__device__ __forceinline__ unsigned short f2bf(float f) {
  union { float f; unsigned u; } c; c.f = f;
  return (unsigned short)((c.u + 0x7fffu + ((c.u >> 16) & 1u)) >> 16);
}
__device__ __forceinline__ float bf2f(unsigned short h) {
  union { unsigned u; float f; } c; c.u = ((unsigned)h) << 16;
  return c.f;
}
// swap the two 5-bit (h,w) fields within each batch's 1024 rows (involution)
__device__ __forceinline__ int permrow(int m) {
  return (m & ~1023) | ((m & 31) << 5) | ((m >> 5) & 31);
}

// ---- split fp32 activations: row layout [hi(1024) | lo(1024)] bf16 ----
__global__ __launch_bounds__(256) void split_x(const float* __restrict__ src,
                                               unsigned short* __restrict__ dst) {
  int idx = blockIdx.x * 256 + threadIdx.x;
  int m = idx >> 7, k8 = (idx & 127) << 3;
  const float* s = src + (size_t)m * 1024 + k8;
  float4 v0 = *(const float4*)s;
  float4 v1 = *(const float4*)(s + 4);
  float vals[8] = {v0.x, v0.y, v0.z, v0.w, v1.x, v1.y, v1.z, v1.w};
  u16x8 hi, lo;
#pragma unroll
  for (int i = 0; i < 8; ++i) {
    unsigned short h = f2bf(vals[i]);
    hi[i] = h;
    lo[i] = f2bf(vals[i] - bf2f(h));
  }
  unsigned short* d = dst + (size_t)m * 2048 + k8;
  *(u16x8*)(d)        = hi;
  *(u16x8*)(d + 1024) = lo;
}

// ---- split fp32 weights into tripled [hi | lo | hi] bf16 ----
__global__ __launch_bounds__(256) void split_w(const float* __restrict__ src,
                                               unsigned short* __restrict__ dst) {
  int idx = blockIdx.x * 256 + threadIdx.x;
  int n = idx >> 7, k8 = (idx & 127) << 3;
  const float* s = src + (size_t)n * 1024 + k8;
  float4 v0 = *(const float4*)s;
  float4 v1 = *(const float4*)(s + 4);
  float vals[8] = {v0.x, v0.y, v0.z, v0.w, v1.x, v1.y, v1.z, v1.w};
  u16x8 hi, lo;
#pragma unroll
  for (int i = 0; i < 8; ++i) {
    unsigned short h = f2bf(vals[i]);
    hi[i] = h;
    lo[i] = f2bf(vals[i] - bf2f(h));
  }
  unsigned short* d = dst + (size_t)n * N3 + k8;
  *(u16x8*)(d)        = hi;
  *(u16x8*)(d + 1024) = lo;
  *(u16x8*)(d + 2048) = hi;
}

// ================= 256x256 8-wave GEMM, 1-barrier-per-K-tile ==============
// C[m][n] = sum over logical K=3072: seg0 Ahi*Bhi, seg1 Ahi*Blo, seg2 Alo*Bhi
// A row layout [hi|lo] stride 2048 (rewind at K-tile 16); B tripled stride 3072.
// LDS: 2 bufs x (A 32KB + B 32KB), st_16x32 XOR swizzle via pre-swizzled source.
// Per K-tile: stage next tile (8 gloads), then 24 ds_read_b128 + 64 MFMA as ONE
// straight-line compiler-scheduled block (reads overlap MFMA via fine-grained
// lgkmcnt), then vmcnt(0)+barrier (issue-to-drain = whole tile ~2500cy >> HBM).
// Grid: per-XCD chunks, n-fast inside chunk (FETCH 282MB proven, r6).
__global__ __launch_bounds__(512, 2) void gemm256(const unsigned short* __restrict__ A,
                                                  const unsigned short* __restrict__ Bm,
                                                  unsigned short* __restrict__ Cq) {
  __shared__ unsigned char smem[131072];
  const int tid = threadIdx.x;
  const int w = tid >> 6, l = tid & 63;
  const int wr = w >> 2, wc = w & 3;          // 2 x 4 wave grid

  // XCD-chunked, n-fast within chunk (768 = 8 XCDs x 8 m-panels x 12 n-panels)
  const int bid = blockIdx.x;
  const int xcd = bid & 7, ic = bid >> 3;
  const int m0 = (xcd * 8 + ic / 12) << 8;
  const int n0 = (ic % 12) << 8;

  // staging: wave w owns rows w*32..w*32+31 of each 16KB unit; pre-swizzled k src
  const int ske = ((l & 3) * 8) ^ ((l >= 32) ? 16 : 0);
  const unsigned short* gA0 = A  + (size_t)(m0 + w * 32 + (l >> 2)) * 2048 + ske;
  const unsigned short* gA1 = gA0 + 16 * 2048;
  const unsigned short* gB0 = Bm + (size_t)(n0 + w * 32 + (l >> 2)) * 3072 + ske;
  const unsigned short* gB1 = gB0 + (size_t)16 * 3072;
  int kA = 0, kB = 0;                         // k-elem offset of K-tile being staged

  // swizzled ds_read lane offset (16B frag at row lr, k-group l>>4)
  const int lr = l & 15;
  const int laneoff = ((lr * 64) + ((l >> 4) * 16)) ^ ((lr & 8) << 2);

#define STAGE_A(pb, kk) do { \
    GLDS(gA0 + kA + (kk) * 32, smem + (pb) * 65536 + (4 * w + (kk)) * 1024); \
    GLDS(gA1 + kA + (kk) * 32, smem + (pb) * 65536 + (4 * w + 2 + (kk)) * 1024); } while (0)
#define STAGE_B(pb, kk) do { \
    GLDS(gB0 + kB + (kk) * 32, smem + (pb) * 65536 + 32768 + (4 * w + (kk)) * 1024); \
    GLDS(gB1 + kB + (kk) * 32, smem + (pb) * 65536 + 32768 + (4 * w + 2 + (kk)) * 1024); } while (0)
#define MFMA(af, bf, c) __builtin_amdgcn_mfma_f32_16x16x32_bf16(af, bf, c, 0, 0, 0)

  f32x4 acc[8][4] = {};

  // ---- prologue: stage K-tile 0 into buf 0, drain, sync ----
  STAGE_A(0, 0); STAGE_B(0, 0); STAGE_A(0, 1); STAGE_B(0, 1);
  kA = 64; kB = 64;
  asm volatile("s_waitcnt vmcnt(0)" ::: "memory");
  __builtin_amdgcn_s_barrier();

  for (int t = 0; t < NT; ++t) {
    const int p = t & 1, q = p ^ 1;
    const unsigned char* rb = smem + p * 65536;

    // issue next-tile staging FIRST (8 gloads; lands during this tile's compute)
    if (t < NT - 1) { STAGE_A(q, 0); STAGE_B(q, 0); STAGE_A(q, 1); STAGE_B(q, 1); }

    // whole K-tile as straight-line code: compiler interleaves ds_read_b128
    // with MFMA via fine-grained lgkmcnt (no intra-tile barriers needed:
    // buffer p fully staged+gated at tile entry; staging writes buffer q).
#pragma unroll
    for (int kk = 0; kk < 2; ++kk) {
      const unsigned char* rk = rb + kk * 1024;
      bf16x8 a[8], b[4];
#pragma unroll
      for (int mi = 0; mi < 8; ++mi)
        a[mi] = *(const bf16x8*)(rk + (wr * 8 + mi) * 2048 + laneoff);
#pragma unroll
      for (int ni = 0; ni < 4; ++ni)
        b[ni] = *(const bf16x8*)(rk + 32768 + (wc * 4 + ni) * 2048 + laneoff);
#pragma unroll
      for (int mi = 0; mi < 8; ++mi)
#pragma unroll
        for (int ni = 0; ni < 4; ++ni)
          acc[mi][ni] = MFMA(a[mi], b[ni], acc[mi][ni]);
    }

    // tile end: own stage loads drained (issued ~2500cy ago), then block sync
    if (t < NT - 1) {
      asm volatile("s_waitcnt vmcnt(0)" ::: "memory");
      __builtin_amdgcn_s_barrier();
    }

    kB += 64;
    kA += 64; if (t == 14) kA -= 1024;   // hi-segment rewind: phys(16) = 0
  }

  // ---- epilogue: acc -> bf16 C ----
  const int rq = (l >> 4) * 4;
#pragma unroll
  for (int mi = 0; mi < 8; ++mi)
#pragma unroll
    for (int ni = 0; ni < 4; ++ni) {
      int row = m0 + wr * 128 + mi * 16 + rq;
      int col = n0 + wc * 64 + ni * 16 + lr;
      unsigned short* cp = Cq + (size_t)row * N3 + col;
#pragma unroll
      for (int r = 0; r < 4; ++r)
        cp[(size_t)r * N3] = f2bf(acc[mi][ni][r]);
    }
#undef STAGE_A
#undef STAGE_B
#undef MFMA
}

// ---- per (seq, head): LN(q), LN(k), softmax(q*s @ k^T) @ v; bf16 in ----
// mode 0: write bf16 [hi|lo] rows permrow(m) into a2 (feeds pass-1 GEMM)
// mode 1: write fp32 rows permrow(m) into out (final result)
__global__ __launch_bounds__(256) void attn(const unsigned short* __restrict__ qkv,
                                            const float* __restrict__ gamma,
                                            const float* __restrict__ beta,
                                            float* __restrict__ out,
                                            unsigned short* __restrict__ a2,
                                            int mode) {
  __shared__ float q[32][65], k[32][65], v[32][65];
  __shared__ float pr[32][33];
  __shared__ float mu[64], rs[64], gm[64], bt[64];
  const int tid = threadIdx.x;
  const int s = blockIdx.x >> 4, hd = blockIdx.x & 15;
  const size_t base = (size_t)s * 32 * 3072 + hd * 64;
  if (tid < 64) { gm[tid] = gamma[tid]; bt[tid] = beta[tid]; }
  {
    const int p = tid >> 3, d0 = (tid & 7) * 8;
    size_t r = base + (size_t)p * 3072 + d0;
    u16x8 qa = *(const u16x8*)(qkv + r);
    u16x8 ka = *(const u16x8*)(qkv + r + 1024);
    u16x8 va = *(const u16x8*)(qkv + r + 2048);
#pragma unroll
    for (int j = 0; j < 8; ++j) {
      q[p][d0 + j] = bf2f(qa[j]);
      k[p][d0 + j] = bf2f(ka[j]);
      v[p][d0 + j] = bf2f(va[j]);
    }
  }
  __syncthreads();
  {  // LN stats: 64 rows (q 0-31, k 32-63) x 4 threads each
    const int r = tid >> 2, qt = tid & 3;
    const float* row = (r < 32) ? q[r] : k[r - 32];
    float s1 = 0.f, s2 = 0.f;
#pragma unroll
    for (int d = qt * 16; d < qt * 16 + 16; ++d) { float x = row[d]; s1 += x; s2 += x * x; }
    s1 += __shfl_xor(s1, 1); s2 += __shfl_xor(s2, 1);
    s1 += __shfl_xor(s1, 2); s2 += __shfl_xor(s2, 2);
    if (qt == 0) {
      float m = s1 * 0.015625f;
      mu[r] = m;
      rs[r] = rsqrtf(s2 * 0.015625f - m * m + 1e-5f);
    }
  }
  __syncthreads();
  {
    const int p = tid >> 3, d0 = (tid & 7) * 8;
#pragma unroll
    for (int j = 0; j < 8; ++j) {
      int d = d0 + j;
      q[p][d] = ((q[p][d] - mu[p]) * rs[p] * gm[d] + bt[d]) * SCALE;
      k[p][d] = (k[p][d] - mu[32 + p]) * rs[32 + p] * gm[d] + bt[d];
    }
  }
  __syncthreads();
  {  // logits: 4 per thread
    const int r = tid >> 3, c0 = (tid & 7) * 4;
#pragma unroll
    for (int cc = 0; cc < 4; ++cc) {
      float a = 0.f;
      const float* qr = q[r]; const float* kr = k[c0 + cc];
#pragma unroll
      for (int d = 0; d < 64; ++d) a += qr[d] * kr[d];
      pr[r][c0 + cc] = a;
    }
  }
  __syncthreads();
  {  // softmax: 8 threads per row
    const int r = tid >> 3, c0 = (tid & 7) * 4;
    float e0 = pr[r][c0], e1 = pr[r][c0 + 1], e2 = pr[r][c0 + 2], e3 = pr[r][c0 + 3];
    float mx = fmaxf(fmaxf(e0, e1), fmaxf(e2, e3));
    mx = fmaxf(mx, __shfl_xor(mx, 1));
    mx = fmaxf(mx, __shfl_xor(mx, 2));
    mx = fmaxf(mx, __shfl_xor(mx, 4));
    e0 = __expf(e0 - mx); e1 = __expf(e1 - mx);
    e2 = __expf(e2 - mx); e3 = __expf(e3 - mx);
    float sum = e0 + e1 + e2 + e3;
    sum += __shfl_xor(sum, 1);
    sum += __shfl_xor(sum, 2);
    sum += __shfl_xor(sum, 4);
    float inv = 1.f / sum;
    pr[r][c0] = e0 * inv; pr[r][c0 + 1] = e1 * inv;
    pr[r][c0 + 2] = e2 * inv; pr[r][c0 + 3] = e3 * inv;
  }
  __syncthreads();
  {  // PV + permuted store
    const int p = tid >> 3, d0 = (tid & 7) * 8;
    float o[8] = {};
#pragma unroll
    for (int j = 0; j < 32; ++j) {
      float pj = pr[p][j];
#pragma unroll
      for (int d = 0; d < 8; ++d) o[d] += pj * v[j][d0 + d];
    }
    int pm = permrow(s * 32 + p);
    if (mode == 0) {
      u16x8 hi, lo;
#pragma unroll
      for (int d = 0; d < 8; ++d) {
        unsigned short h = f2bf(o[d]);
        hi[d] = h;
        lo[d] = f2bf(o[d] - bf2f(h));
      }
      unsigned short* dp = a2 + (size_t)pm * 2048 + hd * 64 + d0;
      *(u16x8*)dp          = hi;
      *(u16x8*)(dp + 1024) = lo;
    } else {
      float* op = out + (size_t)pm * 1024 + hd * 64 + d0;
#pragma unroll
      for (int d = 0; d < 8; ++d) op[d] = o[d];
    }
  }
}

extern "C" void kernel_launch(void* const* d_in, const int* in_sizes, int n_in,
                              void* d_out, int out_size, void* d_ws, size_t ws_size,
                              hipStream_t stream) {
  const float* x    = (const float*)d_in[0];
  const float* Wrow = (const float*)d_in[1];
  const float* Wcol = (const float*)d_in[2];
  const float* grow = (const float*)d_in[3];
  const float* brow = (const float*)d_in[4];
  const float* gcol = (const float*)d_in[5];
  const float* bcol = (const float*)d_in[6];
  float* out = (float*)d_out;

  char* ws = (char*)d_ws;
  const size_t szA2 = (size_t)MROWS * 2048 * 2;   // 67108864
  const size_t szB2 = (size_t)N3 * N3 * 2;        // 18874368
  unsigned short* A2   = (unsigned short*)ws;
  unsigned short* B2   = (unsigned short*)(ws + szA2);
  unsigned short* qkvb = (unsigned short*)(ws + szA2 + szB2);  // 16384*3072*2

  // pass 0 (rows)
  split_x<<<8192, 256, 0, stream>>>(x, A2);
  split_w<<<1536, 256, 0, stream>>>(Wrow, B2);
  gemm256<<<768, 512, 0, stream>>>(A2, B2, qkvb);
  attn<<<8192, 256, 0, stream>>>(qkvb, grow, brow, out, A2, 0);  // writes A2 (permuted)
  // pass 1 (cols)
  split_w<<<1536, 256, 0, stream>>>(Wcol, B2);
  gemm256<<<768, 512, 0, stream>>>(A2, B2, qkvb);
  attn<<<8192, 256, 0, stream>>>(qkvb, gcol, bcol, out, A2, 1);  // writes out
}

// Round 9
// 678.932 us; speedup vs baseline: 1.3205x; 1.2791x over previous
//
#include <hip/hip_runtime.h>
#include <hip/hip_bf16.h>
#include <cstdint>

typedef short  bf16x8 __attribute__((ext_vector_type(8)));
typedef float  f32x4  __attribute__((ext_vector_type(4)));
typedef unsigned short u16x8 __attribute__((ext_vector_type(8)));

#define GLDS(gp, lp) __builtin_amdgcn_global_load_lds( \
    (const __attribute__((address_space(1))) void*)(gp), \
    (__attribute__((address_space(3))) void*)(lp), 16, 0, 0)

static constexpr int   MROWS = 16384;   // B*N = 16*1024
static constexpr int   N3    = 3072;    // 3*C
static constexpr int   NT    = 48;      // K-tiles of 64 (logical K = 3072)
static constexpr float SCALE = 0.125f;  // 8/64

__device__ __forceinline__ unsigned short f2bf(float f) {
  union { float f; unsigned u; } c; c.f = f;
  return (unsigned short)((c.u + 0x7fffu + ((c.u >> 16) & 1u)) >> 16);
}
__device__ __forceinline__ float bf2f(unsigned short h) {
  union { unsigned u; float f; } c; c.u = ((unsigned)h) << 16;
  return c.f;
}
// swap the two 5-bit (h,w) fields within each batch's 1024 rows (involution)
__device__ __forceinline__ int permrow(int m) {
  return (m & ~1023) | ((m & 31) << 5) | ((m >> 5) & 31);
}

// ---- split fp32 rows into [hi(1024) | lo(1024)] bf16 (A2 and B2) ----
__global__ __launch_bounds__(256) void split_hl(const float* __restrict__ src,
                                                unsigned short* __restrict__ dst) {
  int idx = blockIdx.x * 256 + threadIdx.x;
  int m = idx >> 7, k8 = (idx & 127) << 3;
  const float* s = src + (size_t)m * 1024 + k8;
  float4 v0 = *(const float4*)s;
  float4 v1 = *(const float4*)(s + 4);
  float vals[8] = {v0.x, v0.y, v0.z, v0.w, v1.x, v1.y, v1.z, v1.w};
  u16x8 hi, lo;
#pragma unroll
  for (int i = 0; i < 8; ++i) {
    unsigned short h = f2bf(vals[i]);
    hi[i] = h;
    lo[i] = f2bf(vals[i] - bf2f(h));
  }
  unsigned short* d = dst + (size_t)m * 2048 + k8;
  *(u16x8*)(d)        = hi;
  *(u16x8*)(d + 1024) = lo;
}

// ================= 256x256 8-wave GEMM, 1-barrier-per-K-tile (r7) =========
// C[m][n] = sum over logical K=3072: seg0 Ahi*Bhi, seg1 Ahi*Blo, seg2 Alo*Bhi
// A,B row layout [hi|lo] stride 2048; kA rewind after t==14, kB after t==30.
// LDS: 2 bufs x (A 32KB + B 32KB), st_16x32 XOR swizzle via pre-swizzled source.
__global__ __launch_bounds__(512, 2) void gemm256(const unsigned short* __restrict__ A,
                                                  const unsigned short* __restrict__ Bm,
                                                  unsigned short* __restrict__ Cq) {
  __shared__ unsigned char smem[131072];
  const int tid = threadIdx.x;
  const int w = tid >> 6, l = tid & 63;
  const int wr = w >> 2, wc = w & 3;          // 2 x 4 wave grid

  // XCD-chunked, n-fast within chunk (768 = 8 XCDs x 8 m-panels x 12 n-panels)
  const int bid = blockIdx.x;
  const int xcd = bid & 7, ic = bid >> 3;
  const int m0 = (xcd * 8 + ic / 12) << 8;
  const int n0 = (ic % 12) << 8;

  // staging: wave w owns rows w*32..w*32+31 of each 16KB unit; pre-swizzled k src
  const int ske = ((l & 3) * 8) ^ ((l >= 32) ? 16 : 0);
  const unsigned short* gA0 = A  + (size_t)(m0 + w * 32 + (l >> 2)) * 2048 + ske;
  const unsigned short* gA1 = gA0 + 16 * 2048;
  const unsigned short* gB0 = Bm + (size_t)(n0 + w * 32 + (l >> 2)) * 2048 + ske;
  const unsigned short* gB1 = gB0 + 16 * 2048;
  int kA = 0, kB = 0;                         // k-elem offset of K-tile being staged

  // swizzled ds_read lane offset (16B frag at row lr, k-group l>>4)
  const int lr = l & 15;
  const int laneoff = ((lr * 64) + ((l >> 4) * 16)) ^ ((lr & 8) << 2);

#define STAGE_A(pb, kk) do { \
    GLDS(gA0 + kA + (kk) * 32, smem + (pb) * 65536 + (4 * w + (kk)) * 1024); \
    GLDS(gA1 + kA + (kk) * 32, smem + (pb) * 65536 + (4 * w + 2 + (kk)) * 1024); } while (0)
#define STAGE_B(pb, kk) do { \
    GLDS(gB0 + kB + (kk) * 32, smem + (pb) * 65536 + 32768 + (4 * w + (kk)) * 1024); \
    GLDS(gB1 + kB + (kk) * 32, smem + (pb) * 65536 + 32768 + (4 * w + 2 + (kk)) * 1024); } while (0)
#define MFMA(af, bf, c) __builtin_amdgcn_mfma_f32_16x16x32_bf16(af, bf, c, 0, 0, 0)

  f32x4 acc[8][4] = {};

  // ---- prologue: stage K-tile 0 into buf 0, drain, sync ----
  STAGE_A(0, 0); STAGE_B(0, 0); STAGE_A(0, 1); STAGE_B(0, 1);
  kA = 64; kB = 64;
  asm volatile("s_waitcnt vmcnt(0)" ::: "memory");
  __builtin_amdgcn_s_barrier();

  for (int t = 0; t < NT; ++t) {
    const int p = t & 1, q = p ^ 1;
    const unsigned char* rb = smem + p * 65536;

    // issue next-tile staging FIRST (8 gloads; lands during this tile's compute)
    if (t < NT - 1) { STAGE_A(q, 0); STAGE_B(q, 0); STAGE_A(q, 1); STAGE_B(q, 1); }

    // whole K-tile straight-line: compiler interleaves ds_read_b128 with MFMA
#pragma unroll
    for (int kk = 0; kk < 2; ++kk) {
      const unsigned char* rk = rb + kk * 1024;
      bf16x8 a[8], b[4];
#pragma unroll
      for (int mi = 0; mi < 8; ++mi)
        a[mi] = *(const bf16x8*)(rk + (wr * 8 + mi) * 2048 + laneoff);
#pragma unroll
      for (int ni = 0; ni < 4; ++ni)
        b[ni] = *(const bf16x8*)(rk + 32768 + (wc * 4 + ni) * 2048 + laneoff);
#pragma unroll
      for (int mi = 0; mi < 8; ++mi)
#pragma unroll
        for (int ni = 0; ni < 4; ++ni)
          acc[mi][ni] = MFMA(a[mi], b[ni], acc[mi][ni]);
    }

    if (t < NT - 1) {
      asm volatile("s_waitcnt vmcnt(0)" ::: "memory");
      __builtin_amdgcn_s_barrier();
    }

    kB += 64; if (t == 30) kB -= 2048;   // B hi-segment rewind (seg2 re-reads hi)
    kA += 64; if (t == 14) kA -= 1024;   // A hi-segment rewind (seg1 re-reads hi)
  }

  // ---- epilogue: acc -> bf16 C ----
  const int rq = (l >> 4) * 4;
#pragma unroll
  for (int mi = 0; mi < 8; ++mi)
#pragma unroll
    for (int ni = 0; ni < 4; ++ni) {
      int row = m0 + wr * 128 + mi * 16 + rq;
      int col = n0 + wc * 64 + ni * 16 + lr;
      unsigned short* cp = Cq + (size_t)row * N3 + col;
#pragma unroll
      for (int r = 0; r < 4; ++r)
        cp[(size_t)r * N3] = f2bf(acc[mi][ni][r]);
    }
#undef STAGE_A
#undef STAGE_B
#undef MFMA
}

// ---- per (seq, head): fused-LN + softmax(q*s @ k^T) @ v; bf16 in ----
// LN fused into stage-in (lane-octet butterfly stats, all in registers).
// k stored TRANSPOSED (kt[64][36]) -> conflict-free float4 logits reads.
// mode 0: write bf16 [hi|lo] rows permrow(m) into a2; mode 1: fp32 to out.
__global__ __launch_bounds__(256) void attn(const unsigned short* __restrict__ qkv,
                                            const float* __restrict__ gamma,
                                            const float* __restrict__ beta,
                                            float* __restrict__ out,
                                            unsigned short* __restrict__ a2,
                                            int mode) {
  __shared__ float q[32][68];    // normalized*SCALE, row-major, 16B-aligned rows
  __shared__ float kt[64][36];   // normalized k, TRANSPOSED [d][seq]
  __shared__ float v[32][68];
  __shared__ float pr[32][36];
  const int tid = threadIdx.x;
  const int s = blockIdx.x >> 4, hd = blockIdx.x & 15;
  const int p = tid >> 3, d0 = (tid & 7) * 8;
  const size_t base = (size_t)s * 32 * 3072 + hd * 64;

  // ---- load + fused LayerNorm ----
  {
    size_t r = base + (size_t)p * 3072 + d0;
    u16x8 qa = *(const u16x8*)(qkv + r);
    u16x8 ka = *(const u16x8*)(qkv + r + 1024);
    u16x8 va = *(const u16x8*)(qkv + r + 2048);
    float qf[8], kf[8];
    float q1 = 0.f, q2 = 0.f, k1 = 0.f, k2 = 0.f;
#pragma unroll
    for (int j = 0; j < 8; ++j) {
      qf[j] = bf2f(qa[j]); kf[j] = bf2f(ka[j]);
      q1 += qf[j]; q2 += qf[j] * qf[j];
      k1 += kf[j]; k2 += kf[j] * kf[j];
    }
#pragma unroll
    for (int m = 1; m <= 4; m <<= 1) {
      q1 += __shfl_xor(q1, m); q2 += __shfl_xor(q2, m);
      k1 += __shfl_xor(k1, m); k2 += __shfl_xor(k2, m);
    }
    float muq = q1 * 0.015625f, muk = k1 * 0.015625f;
    float rsq = rsqrtf(q2 * 0.015625f - muq * muq + 1e-5f);
    float rsk = rsqrtf(k2 * 0.015625f - muk * muk + 1e-5f);
    f32x4 g0 = *(const f32x4*)(gamma + d0);
    f32x4 g1 = *(const f32x4*)(gamma + d0 + 4);
    f32x4 b0 = *(const f32x4*)(beta + d0);
    f32x4 b1 = *(const f32x4*)(beta + d0 + 4);
    f32x4 qn0, qn1, vv0, vv1;
#pragma unroll
    for (int j = 0; j < 4; ++j) {
      qn0[j] = ((qf[j] - muq) * rsq * g0[j] + b0[j]) * SCALE;
      qn1[j] = ((qf[4 + j] - muq) * rsq * g1[j] + b1[j]) * SCALE;
      kt[d0 + j][p]     = (kf[j] - muk) * rsk * g0[j] + b0[j];
      kt[d0 + 4 + j][p] = (kf[4 + j] - muk) * rsk * g1[j] + b1[j];
      vv0[j] = bf2f(va[j]); vv1[j] = bf2f(va[4 + j]);
    }
    *(f32x4*)&q[p][d0]     = qn0;
    *(f32x4*)&q[p][d0 + 4] = qn1;
    *(f32x4*)&v[p][d0]     = vv0;
    *(f32x4*)&v[p][d0 + 4] = vv1;
  }
  __syncthreads();

  // ---- logits: thread (r=p, c0): pr[r][c0..c0+3], all float4 LDS ----
  {
    const int c0 = (tid & 7) * 4;
    float a0 = 0.f, a1 = 0.f, a2f = 0.f, a3 = 0.f;
#pragma unroll
    for (int dc = 0; dc < 16; ++dc) {
      f32x4 qv = *(const f32x4*)&q[p][dc * 4];
      f32x4 k0 = *(const f32x4*)&kt[dc * 4 + 0][c0];
      f32x4 k1 = *(const f32x4*)&kt[dc * 4 + 1][c0];
      f32x4 k2 = *(const f32x4*)&kt[dc * 4 + 2][c0];
      f32x4 k3 = *(const f32x4*)&kt[dc * 4 + 3][c0];
      a0  += qv[0] * k0[0] + qv[1] * k1[0] + qv[2] * k2[0] + qv[3] * k3[0];
      a1  += qv[0] * k0[1] + qv[1] * k1[1] + qv[2] * k2[1] + qv[3] * k3[1];
      a2f += qv[0] * k0[2] + qv[1] * k1[2] + qv[2] * k2[2] + qv[3] * k3[2];
      a3  += qv[0] * k0[3] + qv[1] * k1[3] + qv[2] * k2[3] + qv[3] * k3[3];
    }
    f32x4 res; res[0] = a0; res[1] = a1; res[2] = a2f; res[3] = a3;
    *(f32x4*)&pr[p][c0] = res;
  }
  __syncthreads();

  // ---- softmax rows (8 lanes per row) ----
  {
    const int c0 = (tid & 7) * 4;
    f32x4 e = *(const f32x4*)&pr[p][c0];
    float mx = fmaxf(fmaxf(e[0], e[1]), fmaxf(e[2], e[3]));
#pragma unroll
    for (int m = 1; m <= 4; m <<= 1) mx = fmaxf(mx, __shfl_xor(mx, m));
    e[0] = __expf(e[0] - mx); e[1] = __expf(e[1] - mx);
    e[2] = __expf(e[2] - mx); e[3] = __expf(e[3] - mx);
    float sum = e[0] + e[1] + e[2] + e[3];
#pragma unroll
    for (int m = 1; m <= 4; m <<= 1) sum += __shfl_xor(sum, m);
    float inv = 1.f / sum;
    e[0] *= inv; e[1] *= inv; e[2] *= inv; e[3] *= inv;
    *(f32x4*)&pr[p][c0] = e;
  }
  __syncthreads();

  // ---- PV + permuted store ----
  {
    f32x4 o0 = {0.f, 0.f, 0.f, 0.f}, o1 = {0.f, 0.f, 0.f, 0.f};
#pragma unroll
    for (int j = 0; j < 32; ++j) {
      float pj = pr[p][j];
      f32x4 v0 = *(const f32x4*)&v[j][d0];
      f32x4 v1 = *(const f32x4*)&v[j][d0 + 4];
      o0 += pj * v0;
      o1 += pj * v1;
    }
    int pm = permrow(s * 32 + p);
    if (mode == 0) {
      u16x8 hi, lo;
#pragma unroll
      for (int j = 0; j < 4; ++j) {
        unsigned short h0 = f2bf(o0[j]);
        hi[j] = h0; lo[j] = f2bf(o0[j] - bf2f(h0));
        unsigned short h1 = f2bf(o1[j]);
        hi[4 + j] = h1; lo[4 + j] = f2bf(o1[j] - bf2f(h1));
      }
      unsigned short* dp = a2 + (size_t)pm * 2048 + hd * 64 + d0;
      *(u16x8*)dp          = hi;
      *(u16x8*)(dp + 1024) = lo;
    } else {
      float* op = out + (size_t)pm * 1024 + hd * 64 + d0;
      *(f32x4*)op       = o0;
      *(f32x4*)(op + 4) = o1;
    }
  }
}

extern "C" void kernel_launch(void* const* d_in, const int* in_sizes, int n_in,
                              void* d_out, int out_size, void* d_ws, size_t ws_size,
                              hipStream_t stream) {
  const float* x    = (const float*)d_in[0];
  const float* Wrow = (const float*)d_in[1];
  const float* Wcol = (const float*)d_in[2];
  const float* grow = (const float*)d_in[3];
  const float* brow = (const float*)d_in[4];
  const float* gcol = (const float*)d_in[5];
  const float* bcol = (const float*)d_in[6];
  float* out = (float*)d_out;

  char* ws = (char*)d_ws;
  const size_t szA2 = (size_t)MROWS * 2048 * 2;   // 67108864
  const size_t szB2 = (size_t)N3 * 2048 * 2;      // 12582912
  unsigned short* A2   = (unsigned short*)ws;
  unsigned short* B2   = (unsigned short*)(ws + szA2);
  unsigned short* qkvb = (unsigned short*)(ws + szA2 + szB2);  // 16384*3072*2

  // pass 0 (rows)
  split_hl<<<8192, 256, 0, stream>>>(x, A2);
  split_hl<<<1536, 256, 0, stream>>>(Wrow, B2);
  gemm256<<<768, 512, 0, stream>>>(A2, B2, qkvb);
  attn<<<8192, 256, 0, stream>>>(qkvb, grow, brow, out, A2, 0);  // writes A2 (permuted)
  // pass 1 (cols)
  split_hl<<<1536, 256, 0, stream>>>(Wcol, B2);
  gemm256<<<768, 512, 0, stream>>>(A2, B2, qkvb);
  attn<<<8192, 256, 0, stream>>>(qkvb, gcol, bcol, out, A2, 1);  // writes out
}

// Round 10
// 537.946 us; speedup vs baseline: 1.6665x; 1.2621x over previous
//
#include <hip/hip_runtime.h>
#include <hip/hip_bf16.h>
#include <cstdint>

typedef _Float16 f16x8 __attribute__((ext_vector_type(8)));
typedef float  f32x4  __attribute__((ext_vector_type(4)));
typedef unsigned short u16x8 __attribute__((ext_vector_type(8)));

#define GLDS(gp, lp) __builtin_amdgcn_global_load_lds( \
    (const __attribute__((address_space(1))) void*)(gp), \
    (__attribute__((address_space(3))) void*)(lp), 16, 0, 0)

static constexpr int   MROWS = 16384;   // B*N = 16*1024
static constexpr int   N3    = 3072;    // 3*C
static constexpr int   NT    = 32;      // K-tiles of 64 (logical K = 2048: hi|lo of W)
static constexpr float SCALE = 0.125f;  // 8/64

__device__ __forceinline__ unsigned short f2h_u(float f) {
  union { _Float16 h; unsigned short u; } c; c.h = (_Float16)f; return c.u;
}
__device__ __forceinline__ float h2f(unsigned short u) {
  union { unsigned short u; _Float16 h; } c; c.u = u; return (float)c.h;
}
// swap the two 5-bit (h,w) fields within each batch's 1024 rows (involution)
__device__ __forceinline__ int permrow(int m) {
  return (m & ~1023) | ((m & 31) << 5) | ((m >> 5) & 31);
}

// ---- fp32 -> plain fp16 rows (activations; x_lo never needed: 2-term split) --
__global__ __launch_bounds__(256) void split_h(const float* __restrict__ src,
                                               unsigned short* __restrict__ dst) {
  int idx = blockIdx.x * 256 + threadIdx.x;
  int m = idx >> 7, k8 = (idx & 127) << 3;
  const float* s = src + (size_t)m * 1024 + k8;
  float4 v0 = *(const float4*)s;
  float4 v1 = *(const float4*)(s + 4);
  float vals[8] = {v0.x, v0.y, v0.z, v0.w, v1.x, v1.y, v1.z, v1.w};
  u16x8 hi;
#pragma unroll
  for (int i = 0; i < 8; ++i) hi[i] = f2h_u(vals[i]);
  *(u16x8*)(dst + (size_t)m * 1024 + k8) = hi;
}

// ---- fp32 weights -> [hi(1024) | lo(1024)] fp16 (21-bit W) ----
__global__ __launch_bounds__(256) void split_hl(const float* __restrict__ src,
                                                unsigned short* __restrict__ dst) {
  int idx = blockIdx.x * 256 + threadIdx.x;
  int n = idx >> 7, k8 = (idx & 127) << 3;
  const float* s = src + (size_t)n * 1024 + k8;
  float4 v0 = *(const float4*)s;
  float4 v1 = *(const float4*)(s + 4);
  float vals[8] = {v0.x, v0.y, v0.z, v0.w, v1.x, v1.y, v1.z, v1.w};
  u16x8 hi, lo;
#pragma unroll
  for (int i = 0; i < 8; ++i) {
    unsigned short h = f2h_u(vals[i]);
    hi[i] = h;
    lo[i] = f2h_u(vals[i] - h2f(h));
  }
  unsigned short* d = dst + (size_t)n * 2048 + k8;
  *(u16x8*)(d)        = hi;
  *(u16x8*)(d + 1024) = lo;
}

// ================= 256x256 8-wave fp16 GEMM, 1-barrier-per-K-tile =========
// C[m][n] = sum over logical K=2048: seg0 A·Bhi (k 0..1023), seg1 A·Blo
// (A re-read: kA rewind after t==14). A stride 1024; B [hi|lo] stride 2048.
// Same proven structure as r7-r9: LDS 2 bufs x 32KB x 2, st_16x32 XOR swizzle
// via pre-swizzled source, stage-8-gloads -> straight-line 24 ds_read + 64
// MFMA -> vmcnt(0)+barrier. Grid: per-XCD chunks, n-fast inside chunk.
__global__ __launch_bounds__(512, 2) void gemm256(const unsigned short* __restrict__ A,
                                                  const unsigned short* __restrict__ Bm,
                                                  unsigned short* __restrict__ Cq) {
  __shared__ unsigned char smem[131072];
  const int tid = threadIdx.x;
  const int w = tid >> 6, l = tid & 63;
  const int wr = w >> 2, wc = w & 3;          // 2 x 4 wave grid

  // XCD-chunked, n-fast within chunk (768 = 8 XCDs x 8 m-panels x 12 n-panels)
  const int bid = blockIdx.x;
  const int xcd = bid & 7, ic = bid >> 3;
  const int m0 = (xcd * 8 + ic / 12) << 8;
  const int n0 = (ic % 12) << 8;

  // staging: wave w owns rows w*32..w*32+31 of each 16KB unit; pre-swizzled k src
  const int ske = ((l & 3) * 8) ^ ((l >= 32) ? 16 : 0);
  const unsigned short* gA0 = A  + (size_t)(m0 + w * 32 + (l >> 2)) * 1024 + ske;
  const unsigned short* gA1 = gA0 + 16 * 1024;
  const unsigned short* gB0 = Bm + (size_t)(n0 + w * 32 + (l >> 2)) * 2048 + ske;
  const unsigned short* gB1 = gB0 + 16 * 2048;
  int kA = 0, kB = 0;                         // k-elem offset of K-tile being staged

  // swizzled ds_read lane offset (16B frag at row lr, k-group l>>4)
  const int lr = l & 15;
  const int laneoff = ((lr * 64) + ((l >> 4) * 16)) ^ ((lr & 8) << 2);

#define STAGE_A(pb, kk) do { \
    GLDS(gA0 + kA + (kk) * 32, smem + (pb) * 65536 + (4 * w + (kk)) * 1024); \
    GLDS(gA1 + kA + (kk) * 32, smem + (pb) * 65536 + (4 * w + 2 + (kk)) * 1024); } while (0)
#define STAGE_B(pb, kk) do { \
    GLDS(gB0 + kB + (kk) * 32, smem + (pb) * 65536 + 32768 + (4 * w + (kk)) * 1024); \
    GLDS(gB1 + kB + (kk) * 32, smem + (pb) * 65536 + 32768 + (4 * w + 2 + (kk)) * 1024); } while (0)
#define MFMA(af, bf, c) __builtin_amdgcn_mfma_f32_16x16x32_f16(af, bf, c, 0, 0, 0)

  f32x4 acc[8][4] = {};

  // ---- prologue: stage K-tile 0 into buf 0, drain, sync ----
  STAGE_A(0, 0); STAGE_B(0, 0); STAGE_A(0, 1); STAGE_B(0, 1);
  kA = 64; kB = 64;
  asm volatile("s_waitcnt vmcnt(0)" ::: "memory");
  __builtin_amdgcn_s_barrier();

  for (int t = 0; t < NT; ++t) {
    const int p = t & 1, q = p ^ 1;
    const unsigned char* rb = smem + p * 65536;

    // issue next-tile staging FIRST (8 gloads; lands during this tile's compute)
    if (t < NT - 1) { STAGE_A(q, 0); STAGE_B(q, 0); STAGE_A(q, 1); STAGE_B(q, 1); }

    // whole K-tile straight-line: compiler interleaves ds_read_b128 with MFMA
#pragma unroll
    for (int kk = 0; kk < 2; ++kk) {
      const unsigned char* rk = rb + kk * 1024;
      f16x8 a[8], b[4];
#pragma unroll
      for (int mi = 0; mi < 8; ++mi)
        a[mi] = *(const f16x8*)(rk + (wr * 8 + mi) * 2048 + laneoff);
#pragma unroll
      for (int ni = 0; ni < 4; ++ni)
        b[ni] = *(const f16x8*)(rk + 32768 + (wc * 4 + ni) * 2048 + laneoff);
#pragma unroll
      for (int mi = 0; mi < 8; ++mi)
#pragma unroll
        for (int ni = 0; ni < 4; ++ni)
          acc[mi][ni] = MFMA(a[mi], b[ni], acc[mi][ni]);
    }

    if (t < NT - 1) {
      asm volatile("s_waitcnt vmcnt(0)" ::: "memory");
      __builtin_amdgcn_s_barrier();
    }

    kB += 64;                            // B walks hi then lo linearly (k 0..2047)
    kA += 64; if (t == 14) kA -= 1024;   // A rewind: seg1 (tiles 16..31) re-reads A
  }

  // ---- epilogue: acc -> fp16 C ----
  const int rq = (l >> 4) * 4;
#pragma unroll
  for (int mi = 0; mi < 8; ++mi)
#pragma unroll
    for (int ni = 0; ni < 4; ++ni) {
      int row = m0 + wr * 128 + mi * 16 + rq;
      int col = n0 + wc * 64 + ni * 16 + lr;
      unsigned short* cp = Cq + (size_t)row * N3 + col;
#pragma unroll
      for (int r = 0; r < 4; ++r)
        cp[(size_t)r * N3] = f2h_u(acc[mi][ni][r]);
    }
#undef STAGE_A
#undef STAGE_B
#undef MFMA
}

// ---- per (seq, head): fused-LN + softmax(q*s @ k^T) @ v; fp16 in ----
// LN fused into stage-in (lane-octet butterfly stats, all in registers).
// k stored TRANSPOSED (kt[64][36]) -> conflict-free float4 logits reads.
// mode 0: write fp16 rows permrow(m) into a2; mode 1: fp32 rows to out.
__global__ __launch_bounds__(256) void attn(const unsigned short* __restrict__ qkv,
                                            const float* __restrict__ gamma,
                                            const float* __restrict__ beta,
                                            float* __restrict__ out,
                                            unsigned short* __restrict__ a2,
                                            int mode) {
  __shared__ float q[32][68];    // normalized*SCALE, row-major, 16B-aligned rows
  __shared__ float kt[64][36];   // normalized k, TRANSPOSED [d][seq]
  __shared__ float v[32][68];
  __shared__ float pr[32][36];
  const int tid = threadIdx.x;
  const int s = blockIdx.x >> 4, hd = blockIdx.x & 15;
  const int p = tid >> 3, d0 = (tid & 7) * 8;
  const size_t base = (size_t)s * 32 * 3072 + hd * 64;

  // ---- load + fused LayerNorm ----
  {
    size_t r = base + (size_t)p * 3072 + d0;
    u16x8 qa = *(const u16x8*)(qkv + r);
    u16x8 ka = *(const u16x8*)(qkv + r + 1024);
    u16x8 va = *(const u16x8*)(qkv + r + 2048);
    float qf[8], kf[8];
    float q1 = 0.f, q2 = 0.f, k1 = 0.f, k2 = 0.f;
#pragma unroll
    for (int j = 0; j < 8; ++j) {
      qf[j] = h2f(qa[j]); kf[j] = h2f(ka[j]);
      q1 += qf[j]; q2 += qf[j] * qf[j];
      k1 += kf[j]; k2 += kf[j] * kf[j];
    }
#pragma unroll
    for (int m = 1; m <= 4; m <<= 1) {
      q1 += __shfl_xor(q1, m); q2 += __shfl_xor(q2, m);
      k1 += __shfl_xor(k1, m); k2 += __shfl_xor(k2, m);
    }
    float muq = q1 * 0.015625f, muk = k1 * 0.015625f;
    float rsq = rsqrtf(q2 * 0.015625f - muq * muq + 1e-5f);
    float rsk = rsqrtf(k2 * 0.015625f - muk * muk + 1e-5f);
    f32x4 g0 = *(const f32x4*)(gamma + d0);
    f32x4 g1 = *(const f32x4*)(gamma + d0 + 4);
    f32x4 b0 = *(const f32x4*)(beta + d0);
    f32x4 b1 = *(const f32x4*)(beta + d0 + 4);
    f32x4 qn0, qn1, vv0, vv1;
#pragma unroll
    for (int j = 0; j < 4; ++j) {
      qn0[j] = ((qf[j] - muq) * rsq * g0[j] + b0[j]) * SCALE;
      qn1[j] = ((qf[4 + j] - muq) * rsq * g1[j] + b1[j]) * SCALE;
      kt[d0 + j][p]     = (kf[j] - muk) * rsk * g0[j] + b0[j];
      kt[d0 + 4 + j][p] = (kf[4 + j] - muk) * rsk * g1[j] + b1[j];
      vv0[j] = h2f(va[j]); vv1[j] = h2f(va[4 + j]);
    }
    *(f32x4*)&q[p][d0]     = qn0;
    *(f32x4*)&q[p][d0 + 4] = qn1;
    *(f32x4*)&v[p][d0]     = vv0;
    *(f32x4*)&v[p][d0 + 4] = vv1;
  }
  __syncthreads();

  // ---- logits: thread (r=p, c0): pr[r][c0..c0+3], all float4 LDS ----
  {
    const int c0 = (tid & 7) * 4;
    float a0 = 0.f, a1 = 0.f, a2f = 0.f, a3 = 0.f;
#pragma unroll
    for (int dc = 0; dc < 16; ++dc) {
      f32x4 qv = *(const f32x4*)&q[p][dc * 4];
      f32x4 k0 = *(const f32x4*)&kt[dc * 4 + 0][c0];
      f32x4 k1 = *(const f32x4*)&kt[dc * 4 + 1][c0];
      f32x4 k2 = *(const f32x4*)&kt[dc * 4 + 2][c0];
      f32x4 k3 = *(const f32x4*)&kt[dc * 4 + 3][c0];
      a0  += qv[0] * k0[0] + qv[1] * k1[0] + qv[2] * k2[0] + qv[3] * k3[0];
      a1  += qv[0] * k0[1] + qv[1] * k1[1] + qv[2] * k2[1] + qv[3] * k3[1];
      a2f += qv[0] * k0[2] + qv[1] * k1[2] + qv[2] * k2[2] + qv[3] * k3[2];
      a3  += qv[0] * k0[3] + qv[1] * k1[3] + qv[2] * k2[3] + qv[3] * k3[3];
    }
    f32x4 res; res[0] = a0; res[1] = a1; res[2] = a2f; res[3] = a3;
    *(f32x4*)&pr[p][c0] = res;
  }
  __syncthreads();

  // ---- softmax rows (8 lanes per row) ----
  {
    const int c0 = (tid & 7) * 4;
    f32x4 e = *(const f32x4*)&pr[p][c0];
    float mx = fmaxf(fmaxf(e[0], e[1]), fmaxf(e[2], e[3]));
#pragma unroll
    for (int m = 1; m <= 4; m <<= 1) mx = fmaxf(mx, __shfl_xor(mx, m));
    e[0] = __expf(e[0] - mx); e[1] = __expf(e[1] - mx);
    e[2] = __expf(e[2] - mx); e[3] = __expf(e[3] - mx);
    float sum = e[0] + e[1] + e[2] + e[3];
#pragma unroll
    for (int m = 1; m <= 4; m <<= 1) sum += __shfl_xor(sum, m);
    float inv = 1.f / sum;
    e[0] *= inv; e[1] *= inv; e[2] *= inv; e[3] *= inv;
    *(f32x4*)&pr[p][c0] = e;
  }
  __syncthreads();

  // ---- PV + permuted store ----
  {
    f32x4 o0 = {0.f, 0.f, 0.f, 0.f}, o1 = {0.f, 0.f, 0.f, 0.f};
#pragma unroll
    for (int j = 0; j < 32; ++j) {
      float pj = pr[p][j];
      f32x4 v0 = *(const f32x4*)&v[j][d0];
      f32x4 v1 = *(const f32x4*)&v[j][d0 + 4];
      o0 += pj * v0;
      o1 += pj * v1;
    }
    int pm = permrow(s * 32 + p);
    if (mode == 0) {
      u16x8 hv;
#pragma unroll
      for (int j = 0; j < 4; ++j) {
        hv[j]     = f2h_u(o0[j]);
        hv[4 + j] = f2h_u(o1[j]);
      }
      *(u16x8*)(a2 + (size_t)pm * 1024 + hd * 64 + d0) = hv;
    } else {
      float* op = out + (size_t)pm * 1024 + hd * 64 + d0;
      *(f32x4*)op       = o0;
      *(f32x4*)(op + 4) = o1;
    }
  }
}

extern "C" void kernel_launch(void* const* d_in, const int* in_sizes, int n_in,
                              void* d_out, int out_size, void* d_ws, size_t ws_size,
                              hipStream_t stream) {
  const float* x    = (const float*)d_in[0];
  const float* Wrow = (const float*)d_in[1];
  const float* Wcol = (const float*)d_in[2];
  const float* grow = (const float*)d_in[3];
  const float* brow = (const float*)d_in[4];
  const float* gcol = (const float*)d_in[5];
  const float* bcol = (const float*)d_in[6];
  float* out = (float*)d_out;

  char* ws = (char*)d_ws;
  const size_t szA2 = (size_t)MROWS * 1024 * 2;   // 33554432
  const size_t szB2 = (size_t)N3 * 2048 * 2;      // 12582912
  unsigned short* A2   = (unsigned short*)ws;
  unsigned short* B2   = (unsigned short*)(ws + szA2);
  unsigned short* qkvh = (unsigned short*)(ws + szA2 + szB2);  // 16384*3072*2

  // pass 0 (rows)
  split_h<<<8192, 256, 0, stream>>>(x, A2);
  split_hl<<<1536, 256, 0, stream>>>(Wrow, B2);
  gemm256<<<768, 512, 0, stream>>>(A2, B2, qkvh);
  attn<<<8192, 256, 0, stream>>>(qkvh, grow, brow, out, A2, 0);  // writes A2 (permuted)
  // pass 1 (cols)
  split_hl<<<1536, 256, 0, stream>>>(Wcol, B2);
  gemm256<<<768, 512, 0, stream>>>(A2, B2, qkvh);
  attn<<<8192, 256, 0, stream>>>(qkvh, gcol, bcol, out, A2, 1);  // writes out
}

// Round 11
// 377.564 us; speedup vs baseline: 2.3745x; 1.4248x over previous
//
#include <hip/hip_runtime.h>
#include <hip/hip_bf16.h>
#include <cstdint>

typedef _Float16 f16x8 __attribute__((ext_vector_type(8)));
typedef float  f32x4  __attribute__((ext_vector_type(4)));
typedef unsigned short u16x8 __attribute__((ext_vector_type(8)));

#define GLDS(gp, lp) __builtin_amdgcn_global_load_lds( \
    (const __attribute__((address_space(1))) void*)(gp), \
    (__attribute__((address_space(3))) void*)(lp), 16, 0, 0)

static constexpr int   MROWS = 16384;   // B*N = 16*1024
static constexpr int   N3    = 3072;    // 3*C
static constexpr int   NT    = 16;      // K-tiles of 64 (K = 1024, single-term fp16)
static constexpr float SCALE = 0.125f;  // 8/64

__device__ __forceinline__ unsigned short f2h_u(float f) {
  union { _Float16 h; unsigned short u; } c; c.h = (_Float16)f; return c.u;
}
__device__ __forceinline__ float h2f(unsigned short u) {
  union { unsigned short u; _Float16 h; } c; c.u = u; return (float)c.h;
}
// swap the two 5-bit (h,w) fields within each batch's 1024 rows (involution)
__device__ __forceinline__ int permrow(int m) {
  return (m & ~1023) | ((m & 31) << 5) | ((m >> 5) & 31);
}

// ---- fp32 -> plain fp16 rows (x and W; single-term quantization) ----
__global__ __launch_bounds__(256) void split_h(const float* __restrict__ src,
                                               unsigned short* __restrict__ dst) {
  int idx = blockIdx.x * 256 + threadIdx.x;
  int m = idx >> 7, k8 = (idx & 127) << 3;
  const float* s = src + (size_t)m * 1024 + k8;
  float4 v0 = *(const float4*)s;
  float4 v1 = *(const float4*)(s + 4);
  float vals[8] = {v0.x, v0.y, v0.z, v0.w, v1.x, v1.y, v1.z, v1.w};
  u16x8 hi;
#pragma unroll
  for (int i = 0; i < 8; ++i) hi[i] = f2h_u(vals[i]);
  *(u16x8*)(dst + (size_t)m * 1024 + k8) = hi;
}

// ================= 256x256 8-wave fp16 GEMM, 1-barrier-per-K-tile =========
// C[m][n] = sum_k A[m][k]*B[n][k], K=1024, both fp16 stride 1024, C fp16.
// Proven r7-r10 structure: LDS 2 bufs x (A 32KB + B 32KB), st_16x32 XOR
// swizzle via pre-swizzled source, stage-8-gloads -> straight-line 24
// ds_read_b128 + 64 MFMA -> vmcnt(0)+barrier. Per-XCD n-fast grid decode.
__global__ __launch_bounds__(512, 2) void gemm256(const unsigned short* __restrict__ A,
                                                  const unsigned short* __restrict__ Bm,
                                                  unsigned short* __restrict__ Cq) {
  __shared__ unsigned char smem[131072];
  const int tid = threadIdx.x;
  const int w = tid >> 6, l = tid & 63;
  const int wr = w >> 2, wc = w & 3;          // 2 x 4 wave grid

  // XCD-chunked, n-fast within chunk (768 = 8 XCDs x 8 m-panels x 12 n-panels)
  const int bid = blockIdx.x;
  const int xcd = bid & 7, ic = bid >> 3;
  const int m0 = (xcd * 8 + ic / 12) << 8;
  const int n0 = (ic % 12) << 8;

  // staging: wave w owns rows w*32..w*32+31 of each 16KB unit; pre-swizzled k src
  const int ske = ((l & 3) * 8) ^ ((l >= 32) ? 16 : 0);
  const unsigned short* gA0 = A  + (size_t)(m0 + w * 32 + (l >> 2)) * 1024 + ske;
  const unsigned short* gA1 = gA0 + 16 * 1024;
  const unsigned short* gB0 = Bm + (size_t)(n0 + w * 32 + (l >> 2)) * 1024 + ske;
  const unsigned short* gB1 = gB0 + 16 * 1024;
  int kT = 0;                                 // k-elem offset of K-tile being staged

  // swizzled ds_read lane offset (16B frag at row lr, k-group l>>4)
  const int lr = l & 15;
  const int laneoff = ((lr * 64) + ((l >> 4) * 16)) ^ ((lr & 8) << 2);

#define STAGE_A(pb, kk) do { \
    GLDS(gA0 + kT + (kk) * 32, smem + (pb) * 65536 + (4 * w + (kk)) * 1024); \
    GLDS(gA1 + kT + (kk) * 32, smem + (pb) * 65536 + (4 * w + 2 + (kk)) * 1024); } while (0)
#define STAGE_B(pb, kk) do { \
    GLDS(gB0 + kT + (kk) * 32, smem + (pb) * 65536 + 32768 + (4 * w + (kk)) * 1024); \
    GLDS(gB1 + kT + (kk) * 32, smem + (pb) * 65536 + 32768 + (4 * w + 2 + (kk)) * 1024); } while (0)
#define MFMA(af, bf, c) __builtin_amdgcn_mfma_f32_16x16x32_f16(af, bf, c, 0, 0, 0)

  f32x4 acc[8][4] = {};

  // ---- prologue: stage K-tile 0 into buf 0, drain, sync ----
  STAGE_A(0, 0); STAGE_B(0, 0); STAGE_A(0, 1); STAGE_B(0, 1);
  kT = 64;
  asm volatile("s_waitcnt vmcnt(0)" ::: "memory");
  __builtin_amdgcn_s_barrier();

  for (int t = 0; t < NT; ++t) {
    const int p = t & 1, q = p ^ 1;
    const unsigned char* rb = smem + p * 65536;

    // issue next-tile staging FIRST (8 gloads; lands during this tile's compute)
    if (t < NT - 1) { STAGE_A(q, 0); STAGE_B(q, 0); STAGE_A(q, 1); STAGE_B(q, 1); }

    // whole K-tile straight-line: compiler interleaves ds_read_b128 with MFMA
#pragma unroll
    for (int kk = 0; kk < 2; ++kk) {
      const unsigned char* rk = rb + kk * 1024;
      f16x8 a[8], b[4];
#pragma unroll
      for (int mi = 0; mi < 8; ++mi)
        a[mi] = *(const f16x8*)(rk + (wr * 8 + mi) * 2048 + laneoff);
#pragma unroll
      for (int ni = 0; ni < 4; ++ni)
        b[ni] = *(const f16x8*)(rk + 32768 + (wc * 4 + ni) * 2048 + laneoff);
#pragma unroll
      for (int mi = 0; mi < 8; ++mi)
#pragma unroll
        for (int ni = 0; ni < 4; ++ni)
          acc[mi][ni] = MFMA(a[mi], b[ni], acc[mi][ni]);
    }

    if (t < NT - 1) {
      asm volatile("s_waitcnt vmcnt(0)" ::: "memory");
      __builtin_amdgcn_s_barrier();
    }
    kT += 64;
  }

  // ---- epilogue: acc -> fp16 C ----
  const int rq = (l >> 4) * 4;
#pragma unroll
  for (int mi = 0; mi < 8; ++mi)
#pragma unroll
    for (int ni = 0; ni < 4; ++ni) {
      int row = m0 + wr * 128 + mi * 16 + rq;
      int col = n0 + wc * 64 + ni * 16 + lr;
      unsigned short* cp = Cq + (size_t)row * N3 + col;
#pragma unroll
      for (int r = 0; r < 4; ++r)
        cp[(size_t)r * N3] = f2h_u(acc[mi][ni][r]);
    }
#undef STAGE_A
#undef STAGE_B
#undef MFMA
}

// ---- per (seq, head): fused-LN + softmax(q*s @ k^T) @ v; fp16 in ----
// LN fused into stage-in (lane-octet butterfly stats, all in registers).
// k stored TRANSPOSED (kt[64][36]) -> conflict-free float4 logits reads.
// mode 0: write fp16 rows permrow(m) into a2; mode 1: fp32 rows to out.
__global__ __launch_bounds__(256) void attn(const unsigned short* __restrict__ qkv,
                                            const float* __restrict__ gamma,
                                            const float* __restrict__ beta,
                                            float* __restrict__ out,
                                            unsigned short* __restrict__ a2,
                                            int mode) {
  __shared__ float q[32][68];    // normalized*SCALE, row-major, 16B-aligned rows
  __shared__ float kt[64][36];   // normalized k, TRANSPOSED [d][seq]
  __shared__ float v[32][68];
  __shared__ float pr[32][36];
  const int tid = threadIdx.x;
  const int s = blockIdx.x >> 4, hd = blockIdx.x & 15;
  const int p = tid >> 3, d0 = (tid & 7) * 8;
  const size_t base = (size_t)s * 32 * 3072 + hd * 64;

  // ---- load + fused LayerNorm ----
  {
    size_t r = base + (size_t)p * 3072 + d0;
    u16x8 qa = *(const u16x8*)(qkv + r);
    u16x8 ka = *(const u16x8*)(qkv + r + 1024);
    u16x8 va = *(const u16x8*)(qkv + r + 2048);
    float qf[8], kf[8];
    float q1 = 0.f, q2 = 0.f, k1 = 0.f, k2 = 0.f;
#pragma unroll
    for (int j = 0; j < 8; ++j) {
      qf[j] = h2f(qa[j]); kf[j] = h2f(ka[j]);
      q1 += qf[j]; q2 += qf[j] * qf[j];
      k1 += kf[j]; k2 += kf[j] * kf[j];
    }
#pragma unroll
    for (int m = 1; m <= 4; m <<= 1) {
      q1 += __shfl_xor(q1, m); q2 += __shfl_xor(q2, m);
      k1 += __shfl_xor(k1, m); k2 += __shfl_xor(k2, m);
    }
    float muq = q1 * 0.015625f, muk = k1 * 0.015625f;
    float rsq = rsqrtf(q2 * 0.015625f - muq * muq + 1e-5f);
    float rsk = rsqrtf(k2 * 0.015625f - muk * muk + 1e-5f);
    f32x4 g0 = *(const f32x4*)(gamma + d0);
    f32x4 g1 = *(const f32x4*)(gamma + d0 + 4);
    f32x4 b0 = *(const f32x4*)(beta + d0);
    f32x4 b1 = *(const f32x4*)(beta + d0 + 4);
    f32x4 qn0, qn1, vv0, vv1;
#pragma unroll
    for (int j = 0; j < 4; ++j) {
      qn0[j] = ((qf[j] - muq) * rsq * g0[j] + b0[j]) * SCALE;
      qn1[j] = ((qf[4 + j] - muq) * rsq * g1[j] + b1[j]) * SCALE;
      kt[d0 + j][p]     = (kf[j] - muk) * rsk * g0[j] + b0[j];
      kt[d0 + 4 + j][p] = (kf[4 + j] - muk) * rsk * g1[j] + b1[j];
      vv0[j] = h2f(va[j]); vv1[j] = h2f(va[4 + j]);
    }
    *(f32x4*)&q[p][d0]     = qn0;
    *(f32x4*)&q[p][d0 + 4] = qn1;
    *(f32x4*)&v[p][d0]     = vv0;
    *(f32x4*)&v[p][d0 + 4] = vv1;
  }
  __syncthreads();

  // ---- logits: thread (r=p, c0): pr[r][c0..c0+3], all float4 LDS ----
  {
    const int c0 = (tid & 7) * 4;
    float a0 = 0.f, a1 = 0.f, a2f = 0.f, a3 = 0.f;
#pragma unroll
    for (int dc = 0; dc < 16; ++dc) {
      f32x4 qv = *(const f32x4*)&q[p][dc * 4];
      f32x4 k0 = *(const f32x4*)&kt[dc * 4 + 0][c0];
      f32x4 k1 = *(const f32x4*)&kt[dc * 4 + 1][c0];
      f32x4 k2 = *(const f32x4*)&kt[dc * 4 + 2][c0];
      f32x4 k3 = *(const f32x4*)&kt[dc * 4 + 3][c0];
      a0  += qv[0] * k0[0] + qv[1] * k1[0] + qv[2] * k2[0] + qv[3] * k3[0];
      a1  += qv[0] * k0[1] + qv[1] * k1[1] + qv[2] * k2[1] + qv[3] * k3[1];
      a2f += qv[0] * k0[2] + qv[1] * k1[2] + qv[2] * k2[2] + qv[3] * k3[2];
      a3  += qv[0] * k0[3] + qv[1] * k1[3] + qv[2] * k2[3] + qv[3] * k3[3];
    }
    f32x4 res; res[0] = a0; res[1] = a1; res[2] = a2f; res[3] = a3;
    *(f32x4*)&pr[p][c0] = res;
  }
  __syncthreads();

  // ---- softmax rows (8 lanes per row) ----
  {
    const int c0 = (tid & 7) * 4;
    f32x4 e = *(const f32x4*)&pr[p][c0];
    float mx = fmaxf(fmaxf(e[0], e[1]), fmaxf(e[2], e[3]));
#pragma unroll
    for (int m = 1; m <= 4; m <<= 1) mx = fmaxf(mx, __shfl_xor(mx, m));
    e[0] = __expf(e[0] - mx); e[1] = __expf(e[1] - mx);
    e[2] = __expf(e[2] - mx); e[3] = __expf(e[3] - mx);
    float sum = e[0] + e[1] + e[2] + e[3];
#pragma unroll
    for (int m = 1; m <= 4; m <<= 1) sum += __shfl_xor(sum, m);
    float inv = 1.f / sum;
    e[0] *= inv; e[1] *= inv; e[2] *= inv; e[3] *= inv;
    *(f32x4*)&pr[p][c0] = e;
  }
  __syncthreads();

  // ---- PV + permuted store ----
  {
    f32x4 o0 = {0.f, 0.f, 0.f, 0.f}, o1 = {0.f, 0.f, 0.f, 0.f};
#pragma unroll
    for (int j = 0; j < 32; ++j) {
      float pj = pr[p][j];
      f32x4 v0 = *(const f32x4*)&v[j][d0];
      f32x4 v1 = *(const f32x4*)&v[j][d0 + 4];
      o0 += pj * v0;
      o1 += pj * v1;
    }
    int pm = permrow(s * 32 + p);
    if (mode == 0) {
      u16x8 hv;
#pragma unroll
      for (int j = 0; j < 4; ++j) {
        hv[j]     = f2h_u(o0[j]);
        hv[4 + j] = f2h_u(o1[j]);
      }
      *(u16x8*)(a2 + (size_t)pm * 1024 + hd * 64 + d0) = hv;
    } else {
      float* op = out + (size_t)pm * 1024 + hd * 64 + d0;
      *(f32x4*)op       = o0;
      *(f32x4*)(op + 4) = o1;
    }
  }
}

extern "C" void kernel_launch(void* const* d_in, const int* in_sizes, int n_in,
                              void* d_out, int out_size, void* d_ws, size_t ws_size,
                              hipStream_t stream) {
  const float* x    = (const float*)d_in[0];
  const float* Wrow = (const float*)d_in[1];
  const float* Wcol = (const float*)d_in[2];
  const float* grow = (const float*)d_in[3];
  const float* brow = (const float*)d_in[4];
  const float* gcol = (const float*)d_in[5];
  const float* bcol = (const float*)d_in[6];
  float* out = (float*)d_out;

  char* ws = (char*)d_ws;
  const size_t szA2 = (size_t)MROWS * 1024 * 2;   // 33554432
  const size_t szB2 = (size_t)N3 * 1024 * 2;      // 6291456
  unsigned short* A2   = (unsigned short*)ws;
  unsigned short* B2   = (unsigned short*)(ws + szA2);
  unsigned short* qkvh = (unsigned short*)(ws + szA2 + szB2);  // 16384*3072*2

  // pass 0 (rows)
  split_h<<<8192, 256, 0, stream>>>(x, A2);
  split_h<<<1536, 256, 0, stream>>>(Wrow, B2);
  gemm256<<<768, 512, 0, stream>>>(A2, B2, qkvh);
  attn<<<8192, 256, 0, stream>>>(qkvh, grow, brow, out, A2, 0);  // writes A2 (permuted)
  // pass 1 (cols)
  split_h<<<1536, 256, 0, stream>>>(Wcol, B2);
  gemm256<<<768, 512, 0, stream>>>(A2, B2, qkvh);
  attn<<<8192, 256, 0, stream>>>(qkvh, gcol, bcol, out, A2, 1);  // writes out
}

// Round 16
// 377.139 us; speedup vs baseline: 2.3771x; 1.0011x over previous
//
#include <hip/hip_runtime.h>
#include <hip/hip_bf16.h>
#include <cstdint>

typedef _Float16 f16x8 __attribute__((ext_vector_type(8)));
typedef float  f32x4  __attribute__((ext_vector_type(4)));
typedef unsigned short u16x8 __attribute__((ext_vector_type(8)));

#define GLDS(gp, lp) __builtin_amdgcn_global_load_lds( \
    (const __attribute__((address_space(1))) void*)(gp), \
    (__attribute__((address_space(3))) void*)(lp), 16, 0, 0)

static constexpr int   MROWS = 16384;   // B*N = 16*1024
static constexpr int   N3    = 3072;    // 3*C
static constexpr int   NT    = 16;      // K-tiles of 64 (K = 1024, single-term fp16)
static constexpr float SCALE = 0.125f;  // 8/64

__device__ __forceinline__ unsigned short f2h_u(float f) {
  union { _Float16 h; unsigned short u; } c; c.h = (_Float16)f; return c.u;
}
__device__ __forceinline__ float h2f(unsigned short u) {
  union { unsigned short u; _Float16 h; } c; c.u = u; return (float)c.h;
}
// swap the two 5-bit (h,w) fields within each batch's 1024 rows (involution)
__device__ __forceinline__ int permrow(int m) {
  return (m & ~1023) | ((m & 31) << 5) | ((m >> 5) & 31);
}

// ---- fp32 -> plain fp16 rows (x and W; single-term quantization) ----
__global__ __launch_bounds__(256) void split_h(const float* __restrict__ src,
                                               unsigned short* __restrict__ dst) {
  int idx = blockIdx.x * 256 + threadIdx.x;
  int m = idx >> 7, k8 = (idx & 127) << 3;
  const float* s = src + (size_t)m * 1024 + k8;
  float4 v0 = *(const float4*)s;
  float4 v1 = *(const float4*)(s + 4);
  float vals[8] = {v0.x, v0.y, v0.z, v0.w, v1.x, v1.y, v1.z, v1.w};
  u16x8 hi;
#pragma unroll
  for (int i = 0; i < 8; ++i) hi[i] = f2h_u(vals[i]);
  *(u16x8*)(dst + (size_t)m * 1024 + k8) = hi;
}

// ================= 256x256 8-wave fp16 GEMM, 1-barrier-per-K-tile =========
// C[m][n] = sum_k A[m][k]*B[n][k], K=1024, both fp16 stride 1024, C fp16.
// Proven r7-r11 structure: LDS 2 bufs x (A 32KB + B 32KB), st_16x32 XOR
// swizzle via pre-swizzled source, stage-8-gloads -> straight-line 24
// ds_read_b128 + 64 MFMA -> vmcnt(0)+barrier. Per-XCD n-fast grid decode.
__global__ __launch_bounds__(512, 2) void gemm256(const unsigned short* __restrict__ A,
                                                  const unsigned short* __restrict__ Bm,
                                                  unsigned short* __restrict__ Cq) {
  __shared__ unsigned char smem[131072];
  const int tid = threadIdx.x;
  const int w = tid >> 6, l = tid & 63;
  const int wr = w >> 2, wc = w & 3;          // 2 x 4 wave grid

  // XCD-chunked, n-fast within chunk (768 = 8 XCDs x 8 m-panels x 12 n-panels)
  const int bid = blockIdx.x;
  const int xcd = bid & 7, ic = bid >> 3;
  const int m0 = (xcd * 8 + ic / 12) << 8;
  const int n0 = (ic % 12) << 8;

  // staging: wave w owns rows w*32..w*32+31 of each 16KB unit; pre-swizzled k src
  const int ske = ((l & 3) * 8) ^ ((l >= 32) ? 16 : 0);
  const unsigned short* gA0 = A  + (size_t)(m0 + w * 32 + (l >> 2)) * 1024 + ske;
  const unsigned short* gA1 = gA0 + 16 * 1024;
  const unsigned short* gB0 = Bm + (size_t)(n0 + w * 32 + (l >> 2)) * 1024 + ske;
  const unsigned short* gB1 = gB0 + 16 * 1024;
  int kT = 0;                                 // k-elem offset of K-tile being staged

  // swizzled ds_read lane offset (16B frag at row lr, k-group l>>4)
  const int lr = l & 15;
  const int laneoff = ((lr * 64) + ((l >> 4) * 16)) ^ ((lr & 8) << 2);

#define STAGE_A(pb, kk) do { \
    GLDS(gA0 + kT + (kk) * 32, smem + (pb) * 65536 + (4 * w + (kk)) * 1024); \
    GLDS(gA1 + kT + (kk) * 32, smem + (pb) * 65536 + (4 * w + 2 + (kk)) * 1024); } while (0)
#define STAGE_B(pb, kk) do { \
    GLDS(gB0 + kT + (kk) * 32, smem + (pb) * 65536 + 32768 + (4 * w + (kk)) * 1024); \
    GLDS(gB1 + kT + (kk) * 32, smem + (pb) * 65536 + 32768 + (4 * w + 2 + (kk)) * 1024); } while (0)
#define MFMA(af, bf, c) __builtin_amdgcn_mfma_f32_16x16x32_f16(af, bf, c, 0, 0, 0)

  f32x4 acc[8][4] = {};

  // ---- prologue: stage K-tile 0 into buf 0, drain, sync ----
  STAGE_A(0, 0); STAGE_B(0, 0); STAGE_A(0, 1); STAGE_B(0, 1);
  kT = 64;
  asm volatile("s_waitcnt vmcnt(0)" ::: "memory");
  __builtin_amdgcn_s_barrier();

  for (int t = 0; t < NT; ++t) {
    const int p = t & 1, q = p ^ 1;
    const unsigned char* rb = smem + p * 65536;

    // issue next-tile staging FIRST (8 gloads; lands during this tile's compute)
    if (t < NT - 1) { STAGE_A(q, 0); STAGE_B(q, 0); STAGE_A(q, 1); STAGE_B(q, 1); }

    // whole K-tile straight-line: compiler interleaves ds_read_b128 with MFMA
#pragma unroll
    for (int kk = 0; kk < 2; ++kk) {
      const unsigned char* rk = rb + kk * 1024;
      f16x8 a[8], b[4];
#pragma unroll
      for (int mi = 0; mi < 8; ++mi)
        a[mi] = *(const f16x8*)(rk + (wr * 8 + mi) * 2048 + laneoff);
#pragma unroll
      for (int ni = 0; ni < 4; ++ni)
        b[ni] = *(const f16x8*)(rk + 32768 + (wc * 4 + ni) * 2048 + laneoff);
#pragma unroll
      for (int mi = 0; mi < 8; ++mi)
#pragma unroll
        for (int ni = 0; ni < 4; ++ni)
          acc[mi][ni] = MFMA(a[mi], b[ni], acc[mi][ni]);
    }

    if (t < NT - 1) {
      asm volatile("s_waitcnt vmcnt(0)" ::: "memory");
      __builtin_amdgcn_s_barrier();
    }
    kT += 64;
  }

  // ---- epilogue: acc -> fp16 C ----
  const int rq = (l >> 4) * 4;
#pragma unroll
  for (int mi = 0; mi < 8; ++mi)
#pragma unroll
    for (int ni = 0; ni < 4; ++ni) {
      int row = m0 + wr * 128 + mi * 16 + rq;
      int col = n0 + wc * 64 + ni * 16 + lr;
      unsigned short* cp = Cq + (size_t)row * N3 + col;
#pragma unroll
      for (int r = 0; r < 4; ++r)
        cp[(size_t)r * N3] = f2h_u(acc[mi][ni][r]);
    }
#undef STAGE_A
#undef STAGE_B
#undef MFMA
}

// ---- per (seq, head): fused-LN + softmax(q*s @ k^T) @ v; fp16 in ----
// LN fused into stage-in (lane-octet butterfly stats, all in registers).
// k stored TRANSPOSED (kt[64][36]) -> conflict-free float4 logits reads.
// mode 0: write fp16 rows permrow(m) into a2; mode 1: fp32 rows to out.
__global__ __launch_bounds__(256) void attn(const unsigned short* __restrict__ qkv,
                                            const float* __restrict__ gamma,
                                            const float* __restrict__ beta,
                                            float* __restrict__ out,
                                            unsigned short* __restrict__ a2,
                                            int mode) {
  __shared__ float q[32][68];    // normalized*SCALE, row-major, 16B-aligned rows
  __shared__ float kt[64][36];   // normalized k, TRANSPOSED [d][seq]
  __shared__ float v[32][68];
  __shared__ float pr[32][36];
  const int tid = threadIdx.x;
  const int s = blockIdx.x >> 4, hd = blockIdx.x & 15;
  const int p = tid >> 3, d0 = (tid & 7) * 8;
  const size_t base = (size_t)s * 32 * 3072 + hd * 64;

  // ---- load + fused LayerNorm ----
  {
    size_t r = base + (size_t)p * 3072 + d0;
    u16x8 qa = *(const u16x8*)(qkv + r);
    u16x8 ka = *(const u16x8*)(qkv + r + 1024);
    u16x8 va = *(const u16x8*)(qkv + r + 2048);
    float qf[8], kf[8];
    float q1 = 0.f, q2 = 0.f, k1 = 0.f, k2 = 0.f;
#pragma unroll
    for (int j = 0; j < 8; ++j) {
      qf[j] = h2f(qa[j]); kf[j] = h2f(ka[j]);
      q1 += qf[j]; q2 += qf[j] * qf[j];
      k1 += kf[j]; k2 += kf[j] * kf[j];
    }
#pragma unroll
    for (int m = 1; m <= 4; m <<= 1) {
      q1 += __shfl_xor(q1, m); q2 += __shfl_xor(q2, m);
      k1 += __shfl_xor(k1, m); k2 += __shfl_xor(k2, m);
    }
    float muq = q1 * 0.015625f, muk = k1 * 0.015625f;
    float rsq = rsqrtf(q2 * 0.015625f - muq * muq + 1e-5f);
    float rsk = rsqrtf(k2 * 0.015625f - muk * muk + 1e-5f);
    f32x4 g0 = *(const f32x4*)(gamma + d0);
    f32x4 g1 = *(const f32x4*)(gamma + d0 + 4);
    f32x4 b0 = *(const f32x4*)(beta + d0);
    f32x4 b1 = *(const f32x4*)(beta + d0 + 4);
    f32x4 qn0, qn1, vv0, vv1;
#pragma unroll
    for (int j = 0; j < 4; ++j) {
      qn0[j] = ((qf[j] - muq) * rsq * g0[j] + b0[j]) * SCALE;
      qn1[j] = ((qf[4 + j] - muq) * rsq * g1[j] + b1[j]) * SCALE;
      kt[d0 + j][p]     = (kf[j] - muk) * rsk * g0[j] + b0[j];
      kt[d0 + 4 + j][p] = (kf[4 + j] - muk) * rsk * g1[j] + b1[j];
      vv0[j] = h2f(va[j]); vv1[j] = h2f(va[4 + j]);
    }
    *(f32x4*)&q[p][d0]     = qn0;
    *(f32x4*)&q[p][d0 + 4] = qn1;
    *(f32x4*)&v[p][d0]     = vv0;
    *(f32x4*)&v[p][d0 + 4] = vv1;
  }
  __syncthreads();

  // ---- logits: thread (r=p, c0): pr[r][c0..c0+3], all float4 LDS ----
  {
    const int c0 = (tid & 7) * 4;
    float a0 = 0.f, a1 = 0.f, a2f = 0.f, a3 = 0.f;
#pragma unroll
    for (int dc = 0; dc < 16; ++dc) {
      f32x4 qv = *(const f32x4*)&q[p][dc * 4];
      f32x4 k0 = *(const f32x4*)&kt[dc * 4 + 0][c0];
      f32x4 k1 = *(const f32x4*)&kt[dc * 4 + 1][c0];
      f32x4 k2 = *(const f32x4*)&kt[dc * 4 + 2][c0];
      f32x4 k3 = *(const f32x4*)&kt[dc * 4 + 3][c0];
      a0  += qv[0] * k0[0] + qv[1] * k1[0] + qv[2] * k2[0] + qv[3] * k3[0];
      a1  += qv[0] * k0[1] + qv[1] * k1[1] + qv[2] * k2[1] + qv[3] * k3[1];
      a2f += qv[0] * k0[2] + qv[1] * k1[2] + qv[2] * k2[2] + qv[3] * k3[2];
      a3  += qv[0] * k0[3] + qv[1] * k1[3] + qv[2] * k2[3] + qv[3] * k3[3];
    }
    f32x4 res; res[0] = a0; res[1] = a1; res[2] = a2f; res[3] = a3;
    *(f32x4*)&pr[p][c0] = res;
  }
  __syncthreads();

  // ---- softmax rows (8 lanes per row) ----
  {
    const int c0 = (tid & 7) * 4;
    f32x4 e = *(const f32x4*)&pr[p][c0];
    float mx = fmaxf(fmaxf(e[0], e[1]), fmaxf(e[2], e[3]));
#pragma unroll
    for (int m = 1; m <= 4; m <<= 1) mx = fmaxf(mx, __shfl_xor(mx, m));
    e[0] = __expf(e[0] - mx); e[1] = __expf(e[1] - mx);
    e[2] = __expf(e[2] - mx); e[3] = __expf(e[3] - mx);
    float sum = e[0] + e[1] + e[2] + e[3];
#pragma unroll
    for (int m = 1; m <= 4; m <<= 1) sum += __shfl_xor(sum, m);
    float inv = 1.f / sum;
    e[0] *= inv; e[1] *= inv; e[2] *= inv; e[3] *= inv;
    *(f32x4*)&pr[p][c0] = e;
  }
  __syncthreads();

  // ---- PV + permuted store ----
  {
    f32x4 o0 = {0.f, 0.f, 0.f, 0.f}, o1 = {0.f, 0.f, 0.f, 0.f};
#pragma unroll
    for (int j = 0; j < 32; ++j) {
      float pj = pr[p][j];
      f32x4 v0 = *(const f32x4*)&v[j][d0];
      f32x4 v1 = *(const f32x4*)&v[j][d0 + 4];
      o0 += pj * v0;
      o1 += pj * v1;
    }
    int pm = permrow(s * 32 + p);
    if (mode == 0) {
      u16x8 hv;
#pragma unroll
      for (int j = 0; j < 4; ++j) {
        hv[j]     = f2h_u(o0[j]);
        hv[4 + j] = f2h_u(o1[j]);
      }
      *(u16x8*)(a2 + (size_t)pm * 1024 + hd * 64 + d0) = hv;
    } else {
      float* op = out + (size_t)pm * 1024 + hd * 64 + d0;
      *(f32x4*)op       = o0;
      *(f32x4*)(op + 4) = o1;
    }
  }
}

extern "C" void kernel_launch(void* const* d_in, const int* in_sizes, int n_in,
                              void* d_out, int out_size, void* d_ws, size_t ws_size,
                              hipStream_t stream) {
  const float* x    = (const float*)d_in[0];
  const float* Wrow = (const float*)d_in[1];
  const float* Wcol = (const float*)d_in[2];
  const float* grow = (const float*)d_in[3];
  const float* brow = (const float*)d_in[4];
  const float* gcol = (const float*)d_in[5];
  const float* bcol = (const float*)d_in[6];
  float* out = (float*)d_out;

  char* ws = (char*)d_ws;
  const size_t szA2 = (size_t)MROWS * 1024 * 2;   // 33554432
  const size_t szB2 = (size_t)N3 * 1024 * 2;      // 6291456
  unsigned short* A2   = (unsigned short*)ws;
  unsigned short* B2   = (unsigned short*)(ws + szA2);
  unsigned short* qkvh = (unsigned short*)(ws + szA2 + szB2);  // 16384*3072*2

  // pass 0 (rows)
  split_h<<<8192, 256, 0, stream>>>(x, A2);
  split_h<<<1536, 256, 0, stream>>>(Wrow, B2);
  gemm256<<<768, 512, 0, stream>>>(A2, B2, qkvh);
  attn<<<8192, 256, 0, stream>>>(qkvh, grow, brow, out, A2, 0);  // writes A2 (permuted)
  // pass 1 (cols)
  split_h<<<1536, 256, 0, stream>>>(Wcol, B2);
  gemm256<<<768, 512, 0, stream>>>(A2, B2, qkvh);
  attn<<<8192, 256, 0, stream>>>(qkvh, gcol, bcol, out, A2, 1);  // writes out
}

// Round 18
// 354.892 us; speedup vs baseline: 2.5261x; 1.0627x over previous
//
#include <hip/hip_runtime.h>
#include <hip/hip_bf16.h>
#include <cstdint>

typedef _Float16 f16x8 __attribute__((ext_vector_type(8)));
typedef _Float16 f16x2 __attribute__((ext_vector_type(2)));
typedef float  f32x4  __attribute__((ext_vector_type(4)));
typedef unsigned short u16x8 __attribute__((ext_vector_type(8)));

#define GLDS(gp, lp) __builtin_amdgcn_global_load_lds( \
    (const __attribute__((address_space(1))) void*)(gp), \
    (__attribute__((address_space(3))) void*)(lp), 16, 0, 0)

static constexpr int   MROWS = 16384;   // B*N = 16*1024
static constexpr int   N3    = 3072;    // 3*C
static constexpr int   NT    = 16;      // K-tiles of 64 (K = 1024, single-term fp16)
static constexpr float SCALE = 0.125f;  // 8/64

#if __has_builtin(__builtin_amdgcn_fdot2)
#define FDOT2(a, b, c) __builtin_amdgcn_fdot2((a), (b), (c), false)
#else
__device__ __forceinline__ float FDOT2(f16x2 a, f16x2 b, float c) {
  return c + (float)a[0] * (float)b[0] + (float)a[1] * (float)b[1];
}
#endif

__device__ __forceinline__ unsigned short f2h_u(float f) {
  union { _Float16 h; unsigned short u; } c; c.h = (_Float16)f; return c.u;
}
__device__ __forceinline__ float h2f(unsigned short u) {
  union { unsigned short u; _Float16 h; } c; c.u = u; return (float)c.h;
}
// swap the two 5-bit (h,w) fields within each batch's 1024 rows (involution)
__device__ __forceinline__ int permrow(int m) {
  return (m & ~1023) | ((m & 31) << 5) | ((m >> 5) & 31);
}

// ---- fp32 -> plain fp16 rows (x and W; single-term quantization) ----
__global__ __launch_bounds__(256) void split_h(const float* __restrict__ src,
                                               unsigned short* __restrict__ dst) {
  int idx = blockIdx.x * 256 + threadIdx.x;
  int m = idx >> 7, k8 = (idx & 127) << 3;
  const float* s = src + (size_t)m * 1024 + k8;
  float4 v0 = *(const float4*)s;
  float4 v1 = *(const float4*)(s + 4);
  float vals[8] = {v0.x, v0.y, v0.z, v0.w, v1.x, v1.y, v1.z, v1.w};
  u16x8 hi;
#pragma unroll
  for (int i = 0; i < 8; ++i) hi[i] = f2h_u(vals[i]);
  *(u16x8*)(dst + (size_t)m * 1024 + k8) = hi;
}

// ================= 256x256 8-wave fp16 GEMM, 1-barrier-per-K-tile =========
// (r7-r16 proven structure, unchanged)
__global__ __launch_bounds__(512, 2) void gemm256(const unsigned short* __restrict__ A,
                                                  const unsigned short* __restrict__ Bm,
                                                  unsigned short* __restrict__ Cq) {
  __shared__ unsigned char smem[131072];
  const int tid = threadIdx.x;
  const int w = tid >> 6, l = tid & 63;
  const int wr = w >> 2, wc = w & 3;          // 2 x 4 wave grid

  // XCD-chunked, n-fast within chunk (768 = 8 XCDs x 8 m-panels x 12 n-panels)
  const int bid = blockIdx.x;
  const int xcd = bid & 7, ic = bid >> 3;
  const int m0 = (xcd * 8 + ic / 12) << 8;
  const int n0 = (ic % 12) << 8;

  // staging: wave w owns rows w*32..w*32+31 of each 16KB unit; pre-swizzled k src
  const int ske = ((l & 3) * 8) ^ ((l >= 32) ? 16 : 0);
  const unsigned short* gA0 = A  + (size_t)(m0 + w * 32 + (l >> 2)) * 1024 + ske;
  const unsigned short* gA1 = gA0 + 16 * 1024;
  const unsigned short* gB0 = Bm + (size_t)(n0 + w * 32 + (l >> 2)) * 1024 + ske;
  const unsigned short* gB1 = gB0 + 16 * 1024;
  int kT = 0;                                 // k-elem offset of K-tile being staged

  // swizzled ds_read lane offset (16B frag at row lr, k-group l>>4)
  const int lr = l & 15;
  const int laneoff = ((lr * 64) + ((l >> 4) * 16)) ^ ((lr & 8) << 2);

#define STAGE_A(pb, kk) do { \
    GLDS(gA0 + kT + (kk) * 32, smem + (pb) * 65536 + (4 * w + (kk)) * 1024); \
    GLDS(gA1 + kT + (kk) * 32, smem + (pb) * 65536 + (4 * w + 2 + (kk)) * 1024); } while (0)
#define STAGE_B(pb, kk) do { \
    GLDS(gB0 + kT + (kk) * 32, smem + (pb) * 65536 + 32768 + (4 * w + (kk)) * 1024); \
    GLDS(gB1 + kT + (kk) * 32, smem + (pb) * 65536 + 32768 + (4 * w + 2 + (kk)) * 1024); } while (0)
#define MFMA(af, bf, c) __builtin_amdgcn_mfma_f32_16x16x32_f16(af, bf, c, 0, 0, 0)

  f32x4 acc[8][4] = {};

  // ---- prologue: stage K-tile 0 into buf 0, drain, sync ----
  STAGE_A(0, 0); STAGE_B(0, 0); STAGE_A(0, 1); STAGE_B(0, 1);
  kT = 64;
  asm volatile("s_waitcnt vmcnt(0)" ::: "memory");
  __builtin_amdgcn_s_barrier();

  for (int t = 0; t < NT; ++t) {
    const int p = t & 1, q = p ^ 1;
    const unsigned char* rb = smem + p * 65536;

    // issue next-tile staging FIRST (8 gloads; lands during this tile's compute)
    if (t < NT - 1) { STAGE_A(q, 0); STAGE_B(q, 0); STAGE_A(q, 1); STAGE_B(q, 1); }

    // whole K-tile straight-line: compiler interleaves ds_read_b128 with MFMA
#pragma unroll
    for (int kk = 0; kk < 2; ++kk) {
      const unsigned char* rk = rb + kk * 1024;
      f16x8 a[8], b[4];
#pragma unroll
      for (int mi = 0; mi < 8; ++mi)
        a[mi] = *(const f16x8*)(rk + (wr * 8 + mi) * 2048 + laneoff);
#pragma unroll
      for (int ni = 0; ni < 4; ++ni)
        b[ni] = *(const f16x8*)(rk + 32768 + (wc * 4 + ni) * 2048 + laneoff);
#pragma unroll
      for (int mi = 0; mi < 8; ++mi)
#pragma unroll
        for (int ni = 0; ni < 4; ++ni)
          acc[mi][ni] = MFMA(a[mi], b[ni], acc[mi][ni]);
    }

    if (t < NT - 1) {
      asm volatile("s_waitcnt vmcnt(0)" ::: "memory");
      __builtin_amdgcn_s_barrier();
    }
    kT += 64;
  }

  // ---- epilogue: acc -> fp16 C ----
  const int rq = (l >> 4) * 4;
#pragma unroll
  for (int mi = 0; mi < 8; ++mi)
#pragma unroll
    for (int ni = 0; ni < 4; ++ni) {
      int row = m0 + wr * 128 + mi * 16 + rq;
      int col = n0 + wc * 64 + ni * 16 + lr;
      unsigned short* cp = Cq + (size_t)row * N3 + col;
#pragma unroll
      for (int r = 0; r < 4; ++r)
        cp[(size_t)r * N3] = f2h_u(acc[mi][ni][r]);
    }
#undef STAGE_A
#undef STAGE_B
#undef MFMA
}

// ---- per (seq, head): fused-LN + softmax(q*s @ k^T) @ v; fp16 in ----
// r11 structure/phases/thread-map; LDS diet: q,k fp16 row-major [32][72]
// (64 halves + pad; stride 36 dwords -> q-reads cover all 32 banks exactly
// once), logits via v_dot2_f32_f16, pr row preloaded as f32x4 in PV.
// v/pr stay fp32 (PV numerics identical to r11).
// r17 BUG FIX: qh was [32][40] -- d0 reaches 56, writes need 64+pad -> LDS
// overrun corrupted q rows (absmax 0.666). Now [32][72] like kh.
__global__ __launch_bounds__(256) void attn(const unsigned short* __restrict__ qkv,
                                            const float* __restrict__ gamma,
                                            const float* __restrict__ beta,
                                            float* __restrict__ out,
                                            unsigned short* __restrict__ a2,
                                            int mode) {
  __shared__ _Float16 qh[32][72];  // q_ln*SCALE fp16, 64+8 pad
  __shared__ _Float16 kh[32][72];  // k_ln fp16, 64+8 pad
  __shared__ float v[32][68];      // fp32 (unchanged)
  __shared__ float pr[32][36];
  const int tid = threadIdx.x;
  const int s = blockIdx.x >> 4, hd = blockIdx.x & 15;
  const int p = tid >> 3, d0 = (tid & 7) * 8;
  const size_t base = (size_t)s * 32 * 3072 + hd * 64;

  // ---- load + fused LayerNorm ----
  {
    size_t r = base + (size_t)p * 3072 + d0;
    u16x8 qa = *(const u16x8*)(qkv + r);
    u16x8 ka = *(const u16x8*)(qkv + r + 1024);
    u16x8 va = *(const u16x8*)(qkv + r + 2048);
    float qf[8], kf[8];
    float q1 = 0.f, q2 = 0.f, k1 = 0.f, k2 = 0.f;
#pragma unroll
    for (int j = 0; j < 8; ++j) {
      qf[j] = h2f(qa[j]); kf[j] = h2f(ka[j]);
      q1 += qf[j]; q2 += qf[j] * qf[j];
      k1 += kf[j]; k2 += kf[j] * kf[j];
    }
#pragma unroll
    for (int m = 1; m <= 4; m <<= 1) {
      q1 += __shfl_xor(q1, m); q2 += __shfl_xor(q2, m);
      k1 += __shfl_xor(k1, m); k2 += __shfl_xor(k2, m);
    }
    float muq = q1 * 0.015625f, muk = k1 * 0.015625f;
    float rsq = rsqrtf(q2 * 0.015625f - muq * muq + 1e-5f);
    float rsk = rsqrtf(k2 * 0.015625f - muk * muk + 1e-5f);
    f32x4 g0 = *(const f32x4*)(gamma + d0);
    f32x4 g1 = *(const f32x4*)(gamma + d0 + 4);
    f32x4 b0 = *(const f32x4*)(beta + d0);
    f32x4 b1 = *(const f32x4*)(beta + d0 + 4);
    f16x8 qn16, kn16;
    f32x4 vv0, vv1;
#pragma unroll
    for (int j = 0; j < 8; ++j) {
      float gg = (j < 4) ? g0[j] : g1[j - 4];
      float bb = (j < 4) ? b0[j] : b1[j - 4];
      qn16[j] = (_Float16)(((qf[j] - muq) * rsq * gg + bb) * SCALE);
      kn16[j] = (_Float16)((kf[j] - muk) * rsk * gg + bb);
    }
#pragma unroll
    for (int j = 0; j < 4; ++j) { vv0[j] = h2f(va[j]); vv1[j] = h2f(va[4 + j]); }
    *(f16x8*)&qh[p][d0] = qn16;
    *(f16x8*)&kh[p][d0] = kn16;
    *(f32x4*)&v[p][d0]     = vv0;
    *(f32x4*)&v[p][d0 + 4] = vv1;
  }
  __syncthreads();

  // ---- logits: thread (r=p, c0): pr[r][c0..c0+3] via fdot2 ----
  {
    const int c0 = (tid & 7) * 4;
    float a0 = 0.f, a1 = 0.f, a2f = 0.f, a3 = 0.f;
#pragma unroll
    for (int dc = 0; dc < 8; ++dc) {
      union { f16x8 v8; f16x2 p2[4]; } qa, k0, k1, k2, k3;
      qa.v8 = *(const f16x8*)&qh[p][dc * 8];
      k0.v8 = *(const f16x8*)&kh[c0 + 0][dc * 8];
      k1.v8 = *(const f16x8*)&kh[c0 + 1][dc * 8];
      k2.v8 = *(const f16x8*)&kh[c0 + 2][dc * 8];
      k3.v8 = *(const f16x8*)&kh[c0 + 3][dc * 8];
#pragma unroll
      for (int j = 0; j < 4; ++j) {
        a0  = FDOT2(qa.p2[j], k0.p2[j], a0);
        a1  = FDOT2(qa.p2[j], k1.p2[j], a1);
        a2f = FDOT2(qa.p2[j], k2.p2[j], a2f);
        a3  = FDOT2(qa.p2[j], k3.p2[j], a3);
      }
    }
    f32x4 res; res[0] = a0; res[1] = a1; res[2] = a2f; res[3] = a3;
    *(f32x4*)&pr[p][c0] = res;
  }
  __syncthreads();

  // ---- softmax rows (8 lanes per row) ----
  {
    const int c0 = (tid & 7) * 4;
    f32x4 e = *(const f32x4*)&pr[p][c0];
    float mx = fmaxf(fmaxf(e[0], e[1]), fmaxf(e[2], e[3]));
#pragma unroll
    for (int m = 1; m <= 4; m <<= 1) mx = fmaxf(mx, __shfl_xor(mx, m));
    e[0] = __expf(e[0] - mx); e[1] = __expf(e[1] - mx);
    e[2] = __expf(e[2] - mx); e[3] = __expf(e[3] - mx);
    float sum = e[0] + e[1] + e[2] + e[3];
#pragma unroll
    for (int m = 1; m <= 4; m <<= 1) sum += __shfl_xor(sum, m);
    float inv = 1.f / sum;
    e[0] *= inv; e[1] *= inv; e[2] *= inv; e[3] *= inv;
    *(f32x4*)&pr[p][c0] = e;
  }
  __syncthreads();

  // ---- PV + permuted store (pr row preloaded to registers) ----
  {
    f32x4 prr[8];
#pragma unroll
    for (int jq = 0; jq < 8; ++jq) prr[jq] = *(const f32x4*)&pr[p][jq * 4];
    f32x4 o0 = {0.f, 0.f, 0.f, 0.f}, o1 = {0.f, 0.f, 0.f, 0.f};
#pragma unroll
    for (int j = 0; j < 32; ++j) {
      float pj = prr[j >> 2][j & 3];   // fully unrolled -> compile-time indices
      f32x4 v0 = *(const f32x4*)&v[j][d0];
      f32x4 v1 = *(const f32x4*)&v[j][d0 + 4];
      o0 += pj * v0;
      o1 += pj * v1;
    }
    int pm = permrow(s * 32 + p);
    if (mode == 0) {
      u16x8 hv;
#pragma unroll
      for (int j = 0; j < 4; ++j) {
        hv[j]     = f2h_u(o0[j]);
        hv[4 + j] = f2h_u(o1[j]);
      }
      *(u16x8*)(a2 + (size_t)pm * 1024 + hd * 64 + d0) = hv;
    } else {
      float* op = out + (size_t)pm * 1024 + hd * 64 + d0;
      *(f32x4*)op       = o0;
      *(f32x4*)(op + 4) = o1;
    }
  }
}

extern "C" void kernel_launch(void* const* d_in, const int* in_sizes, int n_in,
                              void* d_out, int out_size, void* d_ws, size_t ws_size,
                              hipStream_t stream) {
  const float* x    = (const float*)d_in[0];
  const float* Wrow = (const float*)d_in[1];
  const float* Wcol = (const float*)d_in[2];
  const float* grow = (const float*)d_in[3];
  const float* brow = (const float*)d_in[4];
  const float* gcol = (const float*)d_in[5];
  const float* bcol = (const float*)d_in[6];
  float* out = (float*)d_out;

  char* ws = (char*)d_ws;
  const size_t szA2 = (size_t)MROWS * 1024 * 2;   // 33554432
  const size_t szB2 = (size_t)N3 * 1024 * 2;      // 6291456
  unsigned short* A2   = (unsigned short*)ws;
  unsigned short* B2   = (unsigned short*)(ws + szA2);
  unsigned short* qkvh = (unsigned short*)(ws + szA2 + szB2);  // 16384*3072*2

  // pass 0 (rows)
  split_h<<<8192, 256, 0, stream>>>(x, A2);
  split_h<<<1536, 256, 0, stream>>>(Wrow, B2);
  gemm256<<<768, 512, 0, stream>>>(A2, B2, qkvh);
  attn<<<8192, 256, 0, stream>>>(qkvh, grow, brow, out, A2, 0);  // writes A2 (permuted)
  // pass 1 (cols)
  split_h<<<1536, 256, 0, stream>>>(Wcol, B2);
  gemm256<<<768, 512, 0, stream>>>(A2, B2, qkvh);
  attn<<<8192, 256, 0, stream>>>(qkvh, gcol, bcol, out, A2, 1);  // writes out
}